// Round 1
// baseline (823.788 us; speedup 1.0000x reference)
//
#include <hip/hip_runtime.h>

#define B_ 8
#define T_ 12
#define N_ 10000
#define E_ 160000
#define NQ_ 24           // B_*T_/4 quads per node in xt
#define EPS_ 1e-5f
#define CAP_ 64          // neighbor bucket capacity (deg ~ Binom(160k,1e-4), max ~40)
#define NC32 313         // ceil(N_/32)
#define NT64 157         // ceil(N_/64) transpose tiles

// workspace byte offsets (16B-aligned)
#define O_PAR     0
#define O_CURA    24576
#define O_CURC    65536
#define O_SLOTA   106496
#define O_SLOTC   2666496
#define O_XT      5226496
// end ~9.07 MB

// par layout: [d][72] composite weights (a*12+t, a = ah,bh,al,bl,cl,ag), then 5x64 bias tails
#define P_TAIL 4608

// ---------------- DPP wave-64 sum (VALU pipe) ----------------
template<int CTRL>
__device__ __forceinline__ float dpp_add(float v) {
    int s = __builtin_amdgcn_update_dpp(0, __float_as_int(v), CTRL, 0xF, 0xF, true);
    return v + __int_as_float(s);
}
__device__ __forceinline__ float wave_sum(float v) {
    v = dpp_add<0x111>(v);   // row_shr:1
    v = dpp_add<0x112>(v);   // row_shr:2
    v = dpp_add<0x114>(v);   // row_shr:4
    v = dpp_add<0x118>(v);   // row_shr:8
    v = dpp_add<0x142>(v);   // row_bcast15
    v = dpp_add<0x143>(v);   // row_bcast31 -> lane63 = total
    return __int_as_float(__builtin_amdgcn_readlane(__float_as_int(v), 63));
}

__device__ __forceinline__ void prep_body(int tid,
    const float* W_ht, const float* b_ht, const float* W_lt, const float* b_lt,
    const float* Ws_h, const float* Wn_h, const float* b_h,
    const float* Ws_l, const float* Wn_l, const float* Wc_l, const float* b_l,
    const float* Whr, const float* bhr, const float* Wlr, const float* blr,
    const float* Wg, float* par)
{
    int t = tid >> 6, d = tid & 63;
    float ah = 0.f, bh = 0.f, al = 0.f, bl = 0.f, cl = 0.f;
    for (int k = 0; k < 64; ++k) {
        float msh = Ws_h[k * 64 + d] + 0.2f * Whr[k * 64 + d];
        float msl = Ws_l[k * 64 + d] + 0.2f * Wlr[k * 64 + d];
        float wht = W_ht[t * 64 + k];
        float wlt = W_lt[t * 64 + k];
        ah += wht * msh;
        bh += wht * Wn_h[k * 64 + d];
        al += wlt * msl;
        bl += wlt * Wn_l[k * 64 + d];
        cl += wlt * Wc_l[k * 64 + d];
    }
    par[d * 72 + 0 * 12 + t] = ah;
    par[d * 72 + 1 * 12 + t] = bh;
    par[d * 72 + 2 * 12 + t] = al;
    par[d * 72 + 3 * 12 + t] = bl;
    par[d * 72 + 4 * 12 + t] = cl;
    par[d * 72 + 5 * 12 + t] = 2.f * Wg[t * 64 + d];

    if (t == 0) {
        float ch0 = b_h[d] + 0.2f * bhr[d];
        float ch1 = 0.f;
        float cl0 = b_l[d] + 0.2f * blr[d];
        float cl1 = 0.f, cl2 = 0.f;
        for (int k = 0; k < 64; ++k) {
            float bht = b_ht[k];
            float blt = b_lt[k];
            float msh = Ws_h[k * 64 + d] + 0.2f * Whr[k * 64 + d];
            float msl = Ws_l[k * 64 + d] + 0.2f * Wlr[k * 64 + d];
            ch0 += bht * msh;
            ch1 += bht * Wn_h[k * 64 + d];
            cl0 += blt * msl;
            cl1 += blt * Wn_l[k * 64 + d];
            cl2 += blt * Wc_l[k * 64 + d];
        }
        par[P_TAIL + 0 * 64 + d] = ch0;
        par[P_TAIL + 1 * 64 + d] = ch1;
        par[P_TAIL + 2 * 64 + d] = cl0;
        par[P_TAIL + 3 * 64 + d] = cl1;
        par[P_TAIL + 4 * 64 + d] = cl2;
    }
}

// ---------------- k1: LDS-tiled transpose + prep + bucket fill (one edge pass) ----------------
// blocks [0,157): transpose; block 157: prep; blocks [158,1408): edge bucket fill
__global__ __launch_bounds__(256) void k1_kernel(
    const float* __restrict__ x, float* __restrict__ xt,
    const int* __restrict__ ei, const int* __restrict__ cei,
    int* __restrict__ curA, int* __restrict__ curC,
    int* __restrict__ slotA, int* __restrict__ slotC,
    const float* W_ht, const float* b_ht, const float* W_lt, const float* b_lt,
    const float* Ws_h, const float* Wn_h, const float* b_h,
    const float* Ws_l, const float* Wn_l, const float* Wc_l, const float* b_l,
    const float* Whr, const float* bhr, const float* Wlr, const float* blr,
    const float* Wg, float* par)
{
    __shared__ float tld[64 * 98];
    const int tid = threadIdx.x;
    const int blk = blockIdx.x;

    if (blk < NT64) {
        const int n0 = blk * 64;
        const int j = tid & 63;
        const int r0 = tid >> 6;
        const bool ok = (n0 + j) < N_;
#pragma unroll
        for (int rr = 0; rr < 24; ++rr) {
            int r = rr * 4 + r0;
            tld[j * 98 + r] = ok ? x[r * N_ + n0 + j] : 0.f;
        }
        __syncthreads();
        float4* xt4 = (float4*)xt;
#pragma unroll
        for (int it = 0; it < 6; ++it) {
            int idx = it * 256 + tid;
            int jj = idx / 24, q = idx - jj * 24;
            if (n0 + jj < N_) {
                float4 v;
                v.x = tld[jj * 98 + 4 * q + 0];
                v.y = tld[jj * 98 + 4 * q + 1];
                v.z = tld[jj * 98 + 4 * q + 2];
                v.w = tld[jj * 98 + 4 * q + 3];
                xt4[(size_t)(n0 + jj) * NQ_ + q] = v;
            }
        }
        return;
    }
    if (blk == NT64) {
        for (int t = tid; t < 768; t += 256)
            prep_body(t, W_ht, b_ht, W_lt, b_lt, Ws_h, Wn_h, b_h, Ws_l, Wn_l, Wc_l,
                      b_l, Whr, bhr, Wlr, blr, Wg, par);
        return;
    }
    int i = (blk - NT64 - 1) * 256 + tid;   // 0 .. 320000
    if (i < E_) {
        int dd = ei[E_ + i];
        int p = atomicAdd(&curA[dd], 1);
        if (p < CAP_) slotA[dd * CAP_ + p] = ei[i];
    } else if (i < 2 * E_) {
        int e = i - E_;
        int dd = cei[E_ + e];
        int p = atomicAdd(&curC[dd], 1);
        if (p < CAP_) slotC[dd * CAP_ + p] = cei[e];
    }
}

// ---------------- main: fused gather + phased per-row compute (32-node tiles) ----------------
// amdgpu_waves_per_eu(4,4): pin occupancy target to 4 waves/SIMD (16 waves/CU) so the
// backend budgets 128 VGPRs and keeps each phase's 24-weight working set register-resident
// instead of rematerializing global loads of `par` inside the row loop (the old 64-VGPR code).
__global__ __launch_bounds__(256) __attribute__((amdgpu_waves_per_eu(4, 4))) void main_kernel(
    const float* __restrict__ x, const float* __restrict__ par,
    const float4* __restrict__ xt4,
    const int* __restrict__ curA, const int* __restrict__ curC,
    const int* __restrict__ slotA, const int* __restrict__ slotC,
    const float* __restrict__ g_hn, const float* __restrict__ b_hn,
    const float* __restrict__ g_ln, const float* __restrict__ b_ln,
    const float* __restrict__ Wa, const float* __restrict__ ba,
    const float* __restrict__ bg, const float* __restrict__ g_gn,
    const float* __restrict__ b_gn,
    float* __restrict__ out)
{
    __shared__ __align__(16) float s_out[3][64 * 33];   // outputs; [0..12KB) aliased as gather partials
    __shared__ __align__(16) float xs[32 * 12];
    __shared__ __align__(16) float as_[32 * 12];
    __shared__ __align__(16) float cs_[32 * 12];
    __shared__ float indA[32];
    __shared__ float indC[32];

    const int tid = threadIdx.x;
    const int lane = tid & 63;
    const int wave = tid >> 6;
    const int b = blockIdx.x & 7;          // consecutive blocks share the node tile (L2 reuse)
    const int n0 = (blockIdx.x >> 3) * 32;
    const int d = lane;

    // ---- stage x slice ----
    {
        int idx = tid;
        int t = idx >> 5, node = idx & 31;
        int n = n0 + node;
        xs[node * 12 + t] = (n < N_) ? x[(b * T_ + t) * N_ + n] : 0.f;
        idx = tid + 256;
        if (idx < 384) {
            t = idx >> 5; node = idx & 31; n = n0 + node;
            xs[node * 12 + t] = (n < N_) ? x[(b * T_ + t) * N_ + n] : 0.f;
        }
    }

    // ---- fused gather: 4 threads per (node,set), 12 channels for this b ----
    {
        float4* P4 = (float4*)&s_out[0][0];             // 256 threads x 3 float4 = 12 KB
        const int p = tid >> 2;                          // 0..63
        const int s = tid & 3;
        const int node = p & 31;
        const int set = p >> 5;                          // 0:A 1:C
        const int n = n0 + node;
        float4 a0 = {0,0,0,0}, a1 = {0,0,0,0}, a2 = {0,0,0,0};
        if (n < N_) {
            const int* sl = (set ? slotC : slotA) + n * CAP_;
            int dgRaw = (set ? curC : curA)[n];
            int dg = dgRaw < CAP_ ? dgRaw : CAP_;
            for (int j = s; j < dg; j += 4) {
                const float4* src = xt4 + (size_t)sl[j] * NQ_ + b * 3;
                float4 v0 = src[0], v1 = src[1], v2 = src[2];
                a0.x += v0.x; a0.y += v0.y; a0.z += v0.z; a0.w += v0.w;
                a1.x += v1.x; a1.y += v1.y; a1.z += v1.z; a1.w += v1.w;
                a2.x += v2.x; a2.y += v2.y; a2.z += v2.z; a2.w += v2.w;
            }
        }
        P4[tid * 3 + 0] = a0;
        P4[tid * 3 + 1] = a1;
        P4[tid * 3 + 2] = a2;
    }
    __syncthreads();
    {
        const float4* P4 = (const float4*)&s_out[0][0];
        if (tid < 192) {
            int p2 = tid / 3, q = tid - p2 * 3;          // pair, quad
            int node = p2 & 31, set = p2 >> 5;
            int n = n0 + node;
            float4 s0 = P4[(p2 * 4 + 0) * 3 + q];
            float4 s1 = P4[(p2 * 4 + 1) * 3 + q];
            float4 s2 = P4[(p2 * 4 + 2) * 3 + q];
            float4 s3 = P4[(p2 * 4 + 3) * 3 + q];
            float4 sum;
            sum.x = (s0.x + s1.x) + (s2.x + s3.x);
            sum.y = (s0.y + s1.y) + (s2.y + s3.y);
            sum.z = (s0.z + s1.z) + (s2.z + s3.z);
            sum.w = (s0.w + s1.w) + (s2.w + s3.w);
            int dgRaw = (n < N_) ? (set ? curC : curA)[n] : 0;
            float inv = 1.f / (float)(dgRaw > 0 ? dgRaw : 1);
            sum.x *= inv; sum.y *= inv; sum.z *= inv; sum.w *= inv;
            ((float4*)(set ? cs_ : as_))[node * 3 + q] = sum;
        } else {
            int i = tid - 192;                           // 0..63: 32 A-flags then 32 C-flags
            int node = i & 31, set = i >> 5;
            int n = n0 + node;
            float f = (n < N_ && (set ? curC : curA)[n] > 0) ? 1.f : 0.f;
            if (set) indC[node] = f; else indA[node] = f;
        }
    }

    __syncthreads();   // as_/cs_/ind ready; gather-partial buffer dead -> s_out reusable

    const float4* wv = (const float4*)(par + d * 72);
    float acch[8], accl[8], accr[8];

    // ---- Phase H: acc_h for 8 rows; only ah/bh weights (24 regs) resident ----
    {
        const float ch0 = par[P_TAIL + 0 * 64 + d];
        const float ch1 = par[P_TAIL + 1 * 64 + d];
        float wh[24];
#pragma unroll
        for (int k = 0; k < 6; ++k) ((float4*)wh)[k] = wv[k];
#pragma unroll
        for (int i = 0; i < 8; ++i) {
            const int nl = wave * 8 + i;
            float u[12], ua[12];
#pragma unroll
            for (int k = 0; k < 3; ++k) {
                ((float4*)u)[k]  = ((const float4*)(xs  + nl * 12))[k];
                ((float4*)ua)[k] = ((const float4*)(as_ + nl * 12))[k];
            }
            float h = ch0 + indA[nl] * ch1;
#pragma unroll
            for (int t = 0; t < 12; ++t) h += u[t] * wh[t] + ua[t] * wh[12 + t];
            acch[i] = h;
        }
    }
    __syncthreads();   // phase fence: keep next phase's weight loads from hoisting up

    // ---- Phase L1: acc_l partial (al/bl weights, 24 regs) ----
    {
        const float cl0 = par[P_TAIL + 2 * 64 + d];
        const float cl1 = par[P_TAIL + 3 * 64 + d];
        const float cl2 = par[P_TAIL + 4 * 64 + d];
        float wl[24];
#pragma unroll
        for (int k = 0; k < 6; ++k) ((float4*)wl)[k] = wv[6 + k];
#pragma unroll
        for (int i = 0; i < 8; ++i) {
            const int nl = wave * 8 + i;
            float u[12], ua[12];
#pragma unroll
            for (int k = 0; k < 3; ++k) {
                ((float4*)u)[k]  = ((const float4*)(xs  + nl * 12))[k];
                ((float4*)ua)[k] = ((const float4*)(as_ + nl * 12))[k];
            }
            float l = cl0 + indA[nl] * cl1 + indC[nl] * cl2;
#pragma unroll
            for (int t = 0; t < 12; ++t) l += u[t] * wl[t] + ua[t] * wl[12 + t];
            accl[i] = l;
        }
    }
    __syncthreads();   // phase fence

    // ---- Phase L2+R: acc_l += uc*cl; acc_r (cl/ag weights, 24 regs) ----
    {
        const float bgd = bg[d];
        float wc[12], wg_[12];
#pragma unroll
        for (int k = 0; k < 3; ++k) ((float4*)wc)[k]  = wv[12 + k];
#pragma unroll
        for (int k = 0; k < 3; ++k) ((float4*)wg_)[k] = wv[15 + k];
#pragma unroll
        for (int i = 0; i < 8; ++i) {
            const int nl = wave * 8 + i;
            float u[12], uc[12];
#pragma unroll
            for (int k = 0; k < 3; ++k) {
                ((float4*)u)[k]  = ((const float4*)(xs  + nl * 12))[k];
                ((float4*)uc)[k] = ((const float4*)(cs_ + nl * 12))[k];
            }
            float l = accl[i];
            float r = bgd;
#pragma unroll
            for (int t = 0; t < 12; ++t) { l += uc[t] * wc[t]; r += u[t] * wg_[t]; }
            accl[i] = l;
            accr[i] = r;
        }
    }
    __syncthreads();   // phase fence before normalize-phase const loads

    // ---- Phase N: stats + norm + merged-logit fuse + stage outputs ----
    {
        const float ghn = g_hn[d], bhn = b_hn[d];
        const float gln = g_ln[d], bln = b_ln[d];
        const float ggn = g_gn[d], bgn = b_gn[d];
        // softmax over 2 logits == sigmoid of (l0-l1): fold Wa/ba into difference form
        const float wd0 = Wa[d * 2 + 0] - Wa[d * 2 + 1];
        const float wd1 = Wa[(64 + d) * 2 + 0] - Wa[(64 + d) * 2 + 1];
        const float bad = ba[0] - ba[1];
#pragma unroll
        for (int i = 0; i < 8; ++i) {
            const int nl = wave * 8 + i;
            const float h = acch[i], l = accl[i], r = accr[i];

            float v0 = wave_sum(h);
            float v1 = wave_sum(h * h);
            float v2 = wave_sum(l);
            float v3 = wave_sum(l * l);
            float v4 = wave_sum(r);
            float v5 = wave_sum(r * r);

            const float mh = v0 * (1.f / 64.f);
            const float varh = fmaxf(v1 * (1.f / 64.f) - mh * mh, 0.f);
            float hn = (h - mh) * rsqrtf(varh + EPS_) * ghn + bhn;
            float high = hn >= 0.f ? hn : 0.1f * hn;

            const float ml = v2 * (1.f / 64.f);
            const float varl = fmaxf(v3 * (1.f / 64.f) - ml * ml, 0.f);
            float lnv = (l - ml) * rsqrtf(varl + EPS_) * gln + bln;
            float low = 0.5f * lnv * (1.f + erff(lnv * 0.70710678118654752f));

            const float mr = v4 * (1.f / 64.f);
            const float varr = fmaxf(v5 * (1.f / 64.f) - mr * mr, 0.f);
            float rn = (r - mr) * rsqrtf(varr + EPS_) * ggn + bgn;

            float S = wave_sum(high * wd0 + low * wd1);
            float a0 = 1.f / (1.f + expf(-(S + bad)));
            float fused = a0 * high + (1.f - a0) * low + 0.3f * high + 0.3f * low + 0.1f * rn;

            s_out[0][d * 33 + nl] = fused;
            s_out[1][d * 33 + nl] = high;
            s_out[2][d * 33 + nl] = low;
        }
    }
    __syncthreads();

    // ---- write-out: float4 stores (scalar LDS reads keep 33-stride conflict-free) ----
    const int off1 = B_ * 64 * N_;
    const int off2 = 2 * B_ * 64 * N_;
#pragma unroll
    for (int e2 = tid; e2 < 64 * 8; e2 += 256) {
        int rr = e2 >> 3, q = e2 & 7;
        int n = n0 + 4 * q;
        if (n < N_) {
            float4 o0, o1, o2;
            o0.x = s_out[0][rr * 33 + 4 * q + 0];
            o0.y = s_out[0][rr * 33 + 4 * q + 1];
            o0.z = s_out[0][rr * 33 + 4 * q + 2];
            o0.w = s_out[0][rr * 33 + 4 * q + 3];
            o1.x = s_out[1][rr * 33 + 4 * q + 0];
            o1.y = s_out[1][rr * 33 + 4 * q + 1];
            o1.z = s_out[1][rr * 33 + 4 * q + 2];
            o1.w = s_out[1][rr * 33 + 4 * q + 3];
            o2.x = s_out[2][rr * 33 + 4 * q + 0];
            o2.y = s_out[2][rr * 33 + 4 * q + 1];
            o2.z = s_out[2][rr * 33 + 4 * q + 2];
            o2.w = s_out[2][rr * 33 + 4 * q + 3];
            float* o = out + (b * 64 + rr) * N_ + n;
            *(float4*)(o)        = o0;
            *(float4*)(o + off1) = o1;
            *(float4*)(o + off2) = o2;
        }
    }
}

extern "C" void kernel_launch(void* const* d_in, const int* in_sizes, int n_in,
                              void* d_out, int out_size, void* d_ws, size_t ws_size,
                              hipStream_t stream)
{
    const float* x   = (const float*)d_in[0];
    const int* ei    = (const int*)d_in[1];
    const int* cei   = (const int*)d_in[2];
    const float* W_ht = (const float*)d_in[3];
    const float* b_ht = (const float*)d_in[4];
    const float* W_lt = (const float*)d_in[5];
    const float* b_lt = (const float*)d_in[6];
    const float* Ws_h = (const float*)d_in[7];
    const float* Wn_h = (const float*)d_in[8];
    const float* b_h  = (const float*)d_in[9];
    const float* Ws_l = (const float*)d_in[10];
    const float* Wn_l = (const float*)d_in[11];
    const float* Wc_l = (const float*)d_in[12];
    const float* b_l  = (const float*)d_in[13];
    const float* Whr  = (const float*)d_in[14];
    const float* bhr  = (const float*)d_in[15];
    const float* Wlr  = (const float*)d_in[16];
    const float* blr  = (const float*)d_in[17];
    const float* g_hn = (const float*)d_in[18];
    const float* b_hn = (const float*)d_in[19];
    const float* g_ln = (const float*)d_in[20];
    const float* b_ln = (const float*)d_in[21];
    const float* Wa   = (const float*)d_in[22];
    const float* ba   = (const float*)d_in[23];
    const float* Wg   = (const float*)d_in[24];
    const float* bg   = (const float*)d_in[25];
    const float* g_gn = (const float*)d_in[26];
    const float* b_gn = (const float*)d_in[27];

    char* ws = (char*)d_ws;
    float* par   = (float*)(ws + O_PAR);
    int* curA    = (int*)(ws + O_CURA);
    int* curC    = (int*)(ws + O_CURC);
    int* slotA   = (int*)(ws + O_SLOTA);
    int* slotC   = (int*)(ws + O_SLOTC);
    float* xt    = (float*)(ws + O_XT);

    hipMemsetAsync(ws + O_CURA, 0, O_SLOTA - O_CURA, stream);

    k1_kernel<<<NT64 + 1 + (2 * E_ + 255) / 256, 256, 0, stream>>>(
        x, xt, ei, cei, curA, curC, slotA, slotC,
        W_ht, b_ht, W_lt, b_lt, Ws_h, Wn_h, b_h,
        Ws_l, Wn_l, Wc_l, b_l, Whr, bhr, Wlr, blr, Wg, par);

    main_kernel<<<NC32 * 8, 256, 0, stream>>>(
        x, par, (const float4*)xt, curA, curC, slotA, slotC,
        g_hn, b_hn, g_ln, b_ln, Wa, ba, bg, g_gn, b_gn, (float*)d_out);
}

// Round 2
// 231.066 us; speedup vs baseline: 3.5652x; 3.5652x over previous
//
#include <hip/hip_runtime.h>

#define B_ 8
#define T_ 12
#define N_ 10000
#define E_ 160000
#define NQ_ 24           // B_*T_/4 quads per node in xt
#define EPS_ 1e-5f
#define CAP_ 64          // neighbor bucket capacity (deg ~ Binom(160k,1e-4), max ~40)
#define NC32 313         // ceil(N_/32)
#define NT64 157         // ceil(N_/64) transpose tiles

// workspace byte offsets (16B-aligned)
#define O_PAR     0
#define O_CURA    24576
#define O_CURC    65536
#define O_SLOTA   106496
#define O_SLOTC   2666496
#define O_XT      5226496
// end ~9.07 MB

// par layout: [d][72] composite weights (a*12+t, a = ah,bh,al,bl,cl,ag), then 5x64 bias tails
#define P_TAIL 4608

// ---------------- DPP wave-64 sum (VALU pipe) ----------------
template<int CTRL>
__device__ __forceinline__ float dpp_add(float v) {
    int s = __builtin_amdgcn_update_dpp(0, __float_as_int(v), CTRL, 0xF, 0xF, true);
    return v + __int_as_float(s);
}
__device__ __forceinline__ float wave_sum(float v) {
    v = dpp_add<0x111>(v);   // row_shr:1
    v = dpp_add<0x112>(v);   // row_shr:2
    v = dpp_add<0x114>(v);   // row_shr:4
    v = dpp_add<0x118>(v);   // row_shr:8
    v = dpp_add<0x142>(v);   // row_bcast15
    v = dpp_add<0x143>(v);   // row_bcast31 -> lane63 = total
    return __int_as_float(__builtin_amdgcn_readlane(__float_as_int(v), 63));
}

__device__ __forceinline__ void prep_body(int tid,
    const float* W_ht, const float* b_ht, const float* W_lt, const float* b_lt,
    const float* Ws_h, const float* Wn_h, const float* b_h,
    const float* Ws_l, const float* Wn_l, const float* Wc_l, const float* b_l,
    const float* Whr, const float* bhr, const float* Wlr, const float* blr,
    const float* Wg, float* par)
{
    int t = tid >> 6, d = tid & 63;
    float ah = 0.f, bh = 0.f, al = 0.f, bl = 0.f, cl = 0.f;
    for (int k = 0; k < 64; ++k) {
        float msh = Ws_h[k * 64 + d] + 0.2f * Whr[k * 64 + d];
        float msl = Ws_l[k * 64 + d] + 0.2f * Wlr[k * 64 + d];
        float wht = W_ht[t * 64 + k];
        float wlt = W_lt[t * 64 + k];
        ah += wht * msh;
        bh += wht * Wn_h[k * 64 + d];
        al += wlt * msl;
        bl += wlt * Wn_l[k * 64 + d];
        cl += wlt * Wc_l[k * 64 + d];
    }
    par[d * 72 + 0 * 12 + t] = ah;
    par[d * 72 + 1 * 12 + t] = bh;
    par[d * 72 + 2 * 12 + t] = al;
    par[d * 72 + 3 * 12 + t] = bl;
    par[d * 72 + 4 * 12 + t] = cl;
    par[d * 72 + 5 * 12 + t] = 2.f * Wg[t * 64 + d];

    if (t == 0) {
        float ch0 = b_h[d] + 0.2f * bhr[d];
        float ch1 = 0.f;
        float cl0 = b_l[d] + 0.2f * blr[d];
        float cl1 = 0.f, cl2 = 0.f;
        for (int k = 0; k < 64; ++k) {
            float bht = b_ht[k];
            float blt = b_lt[k];
            float msh = Ws_h[k * 64 + d] + 0.2f * Whr[k * 64 + d];
            float msl = Ws_l[k * 64 + d] + 0.2f * Wlr[k * 64 + d];
            ch0 += bht * msh;
            ch1 += bht * Wn_h[k * 64 + d];
            cl0 += blt * msl;
            cl1 += blt * Wn_l[k * 64 + d];
            cl2 += blt * Wc_l[k * 64 + d];
        }
        par[P_TAIL + 0 * 64 + d] = ch0;
        par[P_TAIL + 1 * 64 + d] = ch1;
        par[P_TAIL + 2 * 64 + d] = cl0;
        par[P_TAIL + 3 * 64 + d] = cl1;
        par[P_TAIL + 4 * 64 + d] = cl2;
    }
}

// ---------------- k1: LDS-tiled transpose + prep + bucket fill (one edge pass) ----------------
// blocks [0,157): transpose; block 157: prep; blocks [158,1408): edge bucket fill
__global__ __launch_bounds__(256) void k1_kernel(
    const float* __restrict__ x, float* __restrict__ xt,
    const int* __restrict__ ei, const int* __restrict__ cei,
    int* __restrict__ curA, int* __restrict__ curC,
    int* __restrict__ slotA, int* __restrict__ slotC,
    const float* W_ht, const float* b_ht, const float* W_lt, const float* b_lt,
    const float* Ws_h, const float* Wn_h, const float* b_h,
    const float* Ws_l, const float* Wn_l, const float* Wc_l, const float* b_l,
    const float* Whr, const float* bhr, const float* Wlr, const float* blr,
    const float* Wg, float* par)
{
    __shared__ float tld[64 * 98];
    const int tid = threadIdx.x;
    const int blk = blockIdx.x;

    if (blk < NT64) {
        const int n0 = blk * 64;
        const int j = tid & 63;
        const int r0 = tid >> 6;
        const bool ok = (n0 + j) < N_;
#pragma unroll
        for (int rr = 0; rr < 24; ++rr) {
            int r = rr * 4 + r0;
            tld[j * 98 + r] = ok ? x[r * N_ + n0 + j] : 0.f;
        }
        __syncthreads();
        float4* xt4 = (float4*)xt;
#pragma unroll
        for (int it = 0; it < 6; ++it) {
            int idx = it * 256 + tid;
            int jj = idx / 24, q = idx - jj * 24;
            if (n0 + jj < N_) {
                float4 v;
                v.x = tld[jj * 98 + 4 * q + 0];
                v.y = tld[jj * 98 + 4 * q + 1];
                v.z = tld[jj * 98 + 4 * q + 2];
                v.w = tld[jj * 98 + 4 * q + 3];
                xt4[(size_t)(n0 + jj) * NQ_ + q] = v;
            }
        }
        return;
    }
    if (blk == NT64) {
        for (int t = tid; t < 768; t += 256)
            prep_body(t, W_ht, b_ht, W_lt, b_lt, Ws_h, Wn_h, b_h, Ws_l, Wn_l, Wc_l,
                      b_l, Whr, bhr, Wlr, blr, Wg, par);
        return;
    }
    int i = (blk - NT64 - 1) * 256 + tid;   // 0 .. 320000
    if (i < E_) {
        int dd = ei[E_ + i];
        int p = atomicAdd(&curA[dd], 1);
        if (p < CAP_) slotA[dd * CAP_ + p] = ei[i];
    } else if (i < 2 * E_) {
        int e = i - E_;
        int dd = cei[E_ + e];
        int p = atomicAdd(&curC[dd], 1);
        if (p < CAP_) slotC[dd * CAP_ + p] = cei[e];
    }
}

// ---------------- main: fused gather + per-row compute (32-node tiles) ----------------
// LDS reduced to 2 staged output planes (21760 B -> 7 blocks/CU vs 5 at 30208 B);
// `low` is held in 8 registers and staged/written in a second short pass reusing plane 0.
__global__ __launch_bounds__(256, 4) void main_kernel(
    const float* __restrict__ x, const float* __restrict__ par,
    const float4* __restrict__ xt4,
    const int* __restrict__ curA, const int* __restrict__ curC,
    const int* __restrict__ slotA, const int* __restrict__ slotC,
    const float* __restrict__ g_hn, const float* __restrict__ b_hn,
    const float* __restrict__ g_ln, const float* __restrict__ b_ln,
    const float* __restrict__ Wa, const float* __restrict__ ba,
    const float* __restrict__ bg, const float* __restrict__ g_gn,
    const float* __restrict__ b_gn,
    float* __restrict__ out)
{
    __shared__ __align__(16) float s_out[2][64 * 33];   // staged planes; [0..12KB) aliased as gather partials
    __shared__ __align__(16) float xs[32 * 12];
    __shared__ __align__(16) float as_[32 * 12];
    __shared__ __align__(16) float cs_[32 * 12];
    __shared__ float indA[32];
    __shared__ float indC[32];

    const int tid = threadIdx.x;
    const int lane = tid & 63;
    const int wave = tid >> 6;
    const int b = blockIdx.x & 7;          // consecutive blocks share the node tile (L2 reuse)
    const int n0 = (blockIdx.x >> 3) * 32;
    const int d = lane;

    // ---- stage x slice ----
    {
        int idx = tid;
        int t = idx >> 5, node = idx & 31;
        int n = n0 + node;
        xs[node * 12 + t] = (n < N_) ? x[(b * T_ + t) * N_ + n] : 0.f;
        idx = tid + 256;
        if (idx < 384) {
            t = idx >> 5; node = idx & 31; n = n0 + node;
            xs[node * 12 + t] = (n < N_) ? x[(b * T_ + t) * N_ + n] : 0.f;
        }
    }

    // ---- fused gather: 4 threads per (node,set), 12 channels for this b ----
    {
        float4* P4 = (float4*)&s_out[0][0];             // 256 threads x 3 float4 = 12 KB
        const int p = tid >> 2;                          // 0..63
        const int s = tid & 3;
        const int node = p & 31;
        const int set = p >> 5;                          // 0:A 1:C
        const int n = n0 + node;
        float4 a0 = {0,0,0,0}, a1 = {0,0,0,0}, a2 = {0,0,0,0};
        if (n < N_) {
            const int* sl = (set ? slotC : slotA) + n * CAP_;
            int dgRaw = (set ? curC : curA)[n];
            int dg = dgRaw < CAP_ ? dgRaw : CAP_;
            for (int j = s; j < dg; j += 4) {
                const float4* src = xt4 + (size_t)sl[j] * NQ_ + b * 3;
                float4 v0 = src[0], v1 = src[1], v2 = src[2];
                a0.x += v0.x; a0.y += v0.y; a0.z += v0.z; a0.w += v0.w;
                a1.x += v1.x; a1.y += v1.y; a1.z += v1.z; a1.w += v1.w;
                a2.x += v2.x; a2.y += v2.y; a2.z += v2.z; a2.w += v2.w;
            }
        }
        P4[tid * 3 + 0] = a0;
        P4[tid * 3 + 1] = a1;
        P4[tid * 3 + 2] = a2;
    }
    __syncthreads();
    {
        const float4* P4 = (const float4*)&s_out[0][0];
        if (tid < 192) {
            int p2 = tid / 3, q = tid - p2 * 3;          // pair, quad
            int node = p2 & 31, set = p2 >> 5;
            int n = n0 + node;
            float4 s0 = P4[(p2 * 4 + 0) * 3 + q];
            float4 s1 = P4[(p2 * 4 + 1) * 3 + q];
            float4 s2 = P4[(p2 * 4 + 2) * 3 + q];
            float4 s3 = P4[(p2 * 4 + 3) * 3 + q];
            float4 sum;
            sum.x = (s0.x + s1.x) + (s2.x + s3.x);
            sum.y = (s0.y + s1.y) + (s2.y + s3.y);
            sum.z = (s0.z + s1.z) + (s2.z + s3.z);
            sum.w = (s0.w + s1.w) + (s2.w + s3.w);
            int dgRaw = (n < N_) ? (set ? curC : curA)[n] : 0;
            float inv = 1.f / (float)(dgRaw > 0 ? dgRaw : 1);
            sum.x *= inv; sum.y *= inv; sum.z *= inv; sum.w *= inv;
            ((float4*)(set ? cs_ : as_))[node * 3 + q] = sum;
        } else {
            int i = tid - 192;                           // 0..63: 32 A-flags then 32 C-flags
            int node = i & 31, set = i >> 5;
            int n = n0 + node;
            float f = (n < N_ && (set ? curC : curA)[n] > 0) ? 1.f : 0.f;
            if (set) indC[node] = f; else indA[node] = f;
        }
    }

    // ---- per-lane composite weights ----
    float w[72];
    {
        const float4* wv = (const float4*)(par + d * 72);
#pragma unroll
        for (int k = 0; k < 18; ++k) ((float4*)w)[k] = wv[k];
    }
    const float ch0 = par[P_TAIL + 0 * 64 + d], ch1 = par[P_TAIL + 1 * 64 + d];
    const float cl0 = par[P_TAIL + 2 * 64 + d], cl1 = par[P_TAIL + 3 * 64 + d];
    const float cl2 = par[P_TAIL + 4 * 64 + d];
    const float ghn = g_hn[d], bhn = b_hn[d];
    const float gln = g_ln[d], bln = b_ln[d];
    const float ggn = g_gn[d], bgn = b_gn[d];
    const float bgd = bg[d];
    const float wa00 = Wa[d * 2 + 0], wa01 = Wa[d * 2 + 1];
    const float wa10 = Wa[(64 + d) * 2 + 0], wa11 = Wa[(64 + d) * 2 + 1];
    const float ba0 = ba[0], ba1 = ba[1];

    float lowr[8];   // `low` plane held in regs; staged after fused/high are written

    __syncthreads();   // as_/cs_/ind ready; partial buffer dead -> s_out reusable

#pragma unroll 2
    for (int i = 0; i < 8; ++i) {
        const int nl = wave * 8 + i;
        float u[12], ua[12], uc[12];
#pragma unroll
        for (int k = 0; k < 3; ++k) {
            ((float4*)u)[k]  = ((const float4*)(xs  + nl * 12))[k];
            ((float4*)ua)[k] = ((const float4*)(as_ + nl * 12))[k];
            ((float4*)uc)[k] = ((const float4*)(cs_ + nl * 12))[k];
        }
        const float indd = indA[nl], indc = indC[nl];

        float acc_h = ch0 + indd * ch1;
        float acc_l = cl0 + indd * cl1 + indc * cl2;
        float acc_r = bgd;
#pragma unroll
        for (int t = 0; t < 12; ++t) {
            acc_h += u[t] * w[t]      + ua[t] * w[12 + t];
            acc_l += u[t] * w[24 + t] + ua[t] * w[36 + t] + uc[t] * w[48 + t];
            acc_r += u[t] * w[60 + t];
        }

        float v0 = wave_sum(acc_h);
        float v1 = wave_sum(acc_h * acc_h);
        float v2 = wave_sum(acc_l);
        float v3 = wave_sum(acc_l * acc_l);
        float v4 = wave_sum(acc_r);
        float v5 = wave_sum(acc_r * acc_r);

        const float mh = v0 * (1.f / 64.f);
        const float varh = fmaxf(v1 * (1.f / 64.f) - mh * mh, 0.f);
        float hn = (acc_h - mh) * rsqrtf(varh + EPS_) * ghn + bhn;
        float high = hn >= 0.f ? hn : 0.1f * hn;

        const float ml = v2 * (1.f / 64.f);
        const float varl = fmaxf(v3 * (1.f / 64.f) - ml * ml, 0.f);
        float lnv = (acc_l - ml) * rsqrtf(varl + EPS_) * gln + bln;
        float low = 0.5f * lnv * (1.f + erff(lnv * 0.70710678118654752f));

        const float mr = v4 * (1.f / 64.f);
        const float varr = fmaxf(v5 * (1.f / 64.f) - mr * mr, 0.f);
        float rn = (acc_r - mr) * rsqrtf(varr + EPS_) * ggn + bgn;

        float l0v = wave_sum(high * wa00 + low * wa10);
        float l1v = wave_sum(high * wa01 + low * wa11);
        float a0 = 1.f / (1.f + expf((l1v + ba1) - (l0v + ba0)));
        float fused = a0 * high + (1.f - a0) * low + 0.3f * high + 0.3f * low + 0.1f * rn;

        s_out[0][d * 33 + nl] = fused;
        s_out[1][d * 33 + nl] = high;
        lowr[i] = low;
    }
    __syncthreads();

    const int off1 = B_ * 64 * N_;
    const int off2 = 2 * B_ * 64 * N_;
    // ---- pass 1: fused + high ----
    for (int e2 = tid; e2 < 64 * 32; e2 += 256) {
        int r = e2 >> 5, nl = e2 & 31;
        int n = n0 + nl;
        if (n < N_) {
            float* o = out + (b * 64 + r) * N_ + n;
            o[0]    = s_out[0][r * 33 + nl];
            o[off1] = s_out[1][r * 33 + nl];
        }
    }
    __syncthreads();   // planes drained; restage plane 0 with `low`
#pragma unroll
    for (int i = 0; i < 8; ++i)
        s_out[0][d * 33 + wave * 8 + i] = lowr[i];
    __syncthreads();
    // ---- pass 2: low ----
    for (int e2 = tid; e2 < 64 * 32; e2 += 256) {
        int r = e2 >> 5, nl = e2 & 31;
        int n = n0 + nl;
        if (n < N_) {
            out[(b * 64 + r) * N_ + n + off2] = s_out[0][r * 33 + nl];
        }
    }
}

extern "C" void kernel_launch(void* const* d_in, const int* in_sizes, int n_in,
                              void* d_out, int out_size, void* d_ws, size_t ws_size,
                              hipStream_t stream)
{
    const float* x   = (const float*)d_in[0];
    const int* ei    = (const int*)d_in[1];
    const int* cei   = (const int*)d_in[2];
    const float* W_ht = (const float*)d_in[3];
    const float* b_ht = (const float*)d_in[4];
    const float* W_lt = (const float*)d_in[5];
    const float* b_lt = (const float*)d_in[6];
    const float* Ws_h = (const float*)d_in[7];
    const float* Wn_h = (const float*)d_in[8];
    const float* b_h  = (const float*)d_in[9];
    const float* Ws_l = (const float*)d_in[10];
    const float* Wn_l = (const float*)d_in[11];
    const float* Wc_l = (const float*)d_in[12];
    const float* b_l  = (const float*)d_in[13];
    const float* Whr  = (const float*)d_in[14];
    const float* bhr  = (const float*)d_in[15];
    const float* Wlr  = (const float*)d_in[16];
    const float* blr  = (const float*)d_in[17];
    const float* g_hn = (const float*)d_in[18];
    const float* b_hn = (const float*)d_in[19];
    const float* g_ln = (const float*)d_in[20];
    const float* b_ln = (const float*)d_in[21];
    const float* Wa   = (const float*)d_in[22];
    const float* ba   = (const float*)d_in[23];
    const float* Wg   = (const float*)d_in[24];
    const float* bg   = (const float*)d_in[25];
    const float* g_gn = (const float*)d_in[26];
    const float* b_gn = (const float*)d_in[27];

    char* ws = (char*)d_ws;
    float* par   = (float*)(ws + O_PAR);
    int* curA    = (int*)(ws + O_CURA);
    int* curC    = (int*)(ws + O_CURC);
    int* slotA   = (int*)(ws + O_SLOTA);
    int* slotC   = (int*)(ws + O_SLOTC);
    float* xt    = (float*)(ws + O_XT);

    hipMemsetAsync(ws + O_CURA, 0, O_SLOTA - O_CURA, stream);

    k1_kernel<<<NT64 + 1 + (2 * E_ + 255) / 256, 256, 0, stream>>>(
        x, xt, ei, cei, curA, curC, slotA, slotC,
        W_ht, b_ht, W_lt, b_lt, Ws_h, Wn_h, b_h,
        Ws_l, Wn_l, Wc_l, b_l, Whr, bhr, Wlr, blr, Wg, par);

    main_kernel<<<NC32 * 8, 256, 0, stream>>>(
        x, par, (const float4*)xt, curA, curC, slotA, slotC,
        g_hn, b_hn, g_ln, b_ln, Wa, ba, bg, g_gn, b_gn, (float*)d_out);
}

// Round 3
// 216.882 us; speedup vs baseline: 3.7983x; 1.0654x over previous
//
#include <hip/hip_runtime.h>

#define B_ 8
#define T_ 12
#define N_ 10000
#define E_ 160000
#define NQ_ 24           // B_*T_/4 quads per node in xt
#define EPS_ 1e-5f
#define CAP_ 64          // neighbor bucket capacity (deg ~ Binom(160k,1e-4), max ~40)
#define NC32 313         // ceil(N_/32)
#define NT64 157         // ceil(N_/64) transpose tiles

// workspace byte offsets (16B-aligned)
#define O_PAR     0
#define O_CURA    24576
#define O_CURC    65536
#define O_SLOTA   106496
#define O_SLOTC   2666496
#define O_XT      5226496
// end ~9.07 MB

// par layout: [d][72] composite weights (a*12+t, a = ah,bh,al,bl,cl,ag), then 5x64 bias tails
#define P_TAIL 4608

// ---------------- DPP wave-64 sum (VALU pipe) ----------------
template<int CTRL>
__device__ __forceinline__ float dpp_add(float v) {
    int s = __builtin_amdgcn_update_dpp(0, __float_as_int(v), CTRL, 0xF, 0xF, true);
    return v + __int_as_float(s);
}
__device__ __forceinline__ float wave_sum(float v) {
    v = dpp_add<0x111>(v);   // row_shr:1
    v = dpp_add<0x112>(v);   // row_shr:2
    v = dpp_add<0x114>(v);   // row_shr:4
    v = dpp_add<0x118>(v);   // row_shr:8
    v = dpp_add<0x142>(v);   // row_bcast15
    v = dpp_add<0x143>(v);   // row_bcast31 -> lane63 = total
    return __int_as_float(__builtin_amdgcn_readlane(__float_as_int(v), 63));
}

__device__ __forceinline__ void prep_body(int tid,
    const float* W_ht, const float* b_ht, const float* W_lt, const float* b_lt,
    const float* Ws_h, const float* Wn_h, const float* b_h,
    const float* Ws_l, const float* Wn_l, const float* Wc_l, const float* b_l,
    const float* Whr, const float* bhr, const float* Wlr, const float* blr,
    const float* Wg, float* par)
{
    int t = tid >> 6, d = tid & 63;
    float ah = 0.f, bh = 0.f, al = 0.f, bl = 0.f, cl = 0.f;
    for (int k = 0; k < 64; ++k) {
        float msh = Ws_h[k * 64 + d] + 0.2f * Whr[k * 64 + d];
        float msl = Ws_l[k * 64 + d] + 0.2f * Wlr[k * 64 + d];
        float wht = W_ht[t * 64 + k];
        float wlt = W_lt[t * 64 + k];
        ah += wht * msh;
        bh += wht * Wn_h[k * 64 + d];
        al += wlt * msl;
        bl += wlt * Wn_l[k * 64 + d];
        cl += wlt * Wc_l[k * 64 + d];
    }
    par[d * 72 + 0 * 12 + t] = ah;
    par[d * 72 + 1 * 12 + t] = bh;
    par[d * 72 + 2 * 12 + t] = al;
    par[d * 72 + 3 * 12 + t] = bl;
    par[d * 72 + 4 * 12 + t] = cl;
    par[d * 72 + 5 * 12 + t] = 2.f * Wg[t * 64 + d];

    if (t == 0) {
        float ch0 = b_h[d] + 0.2f * bhr[d];
        float ch1 = 0.f;
        float cl0 = b_l[d] + 0.2f * blr[d];
        float cl1 = 0.f, cl2 = 0.f;
        for (int k = 0; k < 64; ++k) {
            float bht = b_ht[k];
            float blt = b_lt[k];
            float msh = Ws_h[k * 64 + d] + 0.2f * Whr[k * 64 + d];
            float msl = Ws_l[k * 64 + d] + 0.2f * Wlr[k * 64 + d];
            ch0 += bht * msh;
            ch1 += bht * Wn_h[k * 64 + d];
            cl0 += blt * msl;
            cl1 += blt * Wn_l[k * 64 + d];
            cl2 += blt * Wc_l[k * 64 + d];
        }
        par[P_TAIL + 0 * 64 + d] = ch0;
        par[P_TAIL + 1 * 64 + d] = ch1;
        par[P_TAIL + 2 * 64 + d] = cl0;
        par[P_TAIL + 3 * 64 + d] = cl1;
        par[P_TAIL + 4 * 64 + d] = cl2;
    }
}

// ---------------- k1: LDS-tiled transpose + prep + bucket fill (one edge pass) ----------------
// blocks [0,157): transpose; block 157: prep; blocks [158,1408): edge bucket fill
__global__ __launch_bounds__(256) void k1_kernel(
    const float* __restrict__ x, float* __restrict__ xt,
    const int* __restrict__ ei, const int* __restrict__ cei,
    int* __restrict__ curA, int* __restrict__ curC,
    int* __restrict__ slotA, int* __restrict__ slotC,
    const float* W_ht, const float* b_ht, const float* W_lt, const float* b_lt,
    const float* Ws_h, const float* Wn_h, const float* b_h,
    const float* Ws_l, const float* Wn_l, const float* Wc_l, const float* b_l,
    const float* Whr, const float* bhr, const float* Wlr, const float* blr,
    const float* Wg, float* par)
{
    __shared__ float tld[64 * 98];
    const int tid = threadIdx.x;
    const int blk = blockIdx.x;

    if (blk < NT64) {
        const int n0 = blk * 64;
        const int j = tid & 63;
        const int r0 = tid >> 6;
        const bool ok = (n0 + j) < N_;
#pragma unroll
        for (int rr = 0; rr < 24; ++rr) {
            int r = rr * 4 + r0;
            tld[j * 98 + r] = ok ? x[r * N_ + n0 + j] : 0.f;
        }
        __syncthreads();
        float4* xt4 = (float4*)xt;
#pragma unroll
        for (int it = 0; it < 6; ++it) {
            int idx = it * 256 + tid;
            int jj = idx / 24, q = idx - jj * 24;
            if (n0 + jj < N_) {
                float4 v;
                v.x = tld[jj * 98 + 4 * q + 0];
                v.y = tld[jj * 98 + 4 * q + 1];
                v.z = tld[jj * 98 + 4 * q + 2];
                v.w = tld[jj * 98 + 4 * q + 3];
                xt4[(size_t)(n0 + jj) * NQ_ + q] = v;
            }
        }
        return;
    }
    if (blk == NT64) {
        for (int t = tid; t < 768; t += 256)
            prep_body(t, W_ht, b_ht, W_lt, b_lt, Ws_h, Wn_h, b_h, Ws_l, Wn_l, Wc_l,
                      b_l, Whr, bhr, Wlr, blr, Wg, par);
        return;
    }
    int i = (blk - NT64 - 1) * 256 + tid;   // 0 .. 320000
    if (i < E_) {
        int dd = ei[E_ + i];
        int p = atomicAdd(&curA[dd], 1);
        if (p < CAP_) slotA[dd * CAP_ + p] = ei[i];
    } else if (i < 2 * E_) {
        int e = i - E_;
        int dd = cei[E_ + e];
        int p = atomicAdd(&curC[dd], 1);
        if (p < CAP_) slotC[dd * CAP_ + p] = cei[e];
    }
}

// ---------------- main: fused gather + per-row compute (32-node tiles) ----------------
// Block->(tile,b) mapping co-locates a tile's 8 b-blocks on ONE XCD (blockIdx%8 = XCD
// round-robin heuristic): xt (3.84 MB) fits the XCD's 4 MB L2, slot lists are fetched
// once and L2-hit 7x, instead of 8 XCDs each re-fetching the same gather data.
__global__ __launch_bounds__(256, 4) void main_kernel(
    const float* __restrict__ x, const float* __restrict__ par,
    const float4* __restrict__ xt4,
    const int* __restrict__ curA, const int* __restrict__ curC,
    const int* __restrict__ slotA, const int* __restrict__ slotC,
    const float* __restrict__ g_hn, const float* __restrict__ b_hn,
    const float* __restrict__ g_ln, const float* __restrict__ b_ln,
    const float* __restrict__ Wa, const float* __restrict__ ba,
    const float* __restrict__ bg, const float* __restrict__ g_gn,
    const float* __restrict__ b_gn,
    float* __restrict__ out)
{
    __shared__ __align__(16) float s_out[3][64 * 33];   // outputs; [0..12KB) aliased as gather partials
    __shared__ __align__(16) float xs[32 * 12];
    __shared__ __align__(16) float as_[32 * 12];
    __shared__ __align__(16) float cs_[32 * 12];
    __shared__ float indA[32];
    __shared__ float indC[32];

    const int tid = threadIdx.x;
    const int lane = tid & 63;
    const int wave = tid >> 6;

    // ---- XCD-co-located (tile, b) decode: xcd = phys%8, 40/39 tiles per XCD ----
    const int xcd  = blockIdx.x & 7;
    const int slot = blockIdx.x >> 3;        // 0..319
    const int g    = slot >> 3;              // tile-group within this XCD, 0..39
    const int b    = slot & 7;
    const int tile = (xcd == 0) ? g : (40 + (xcd - 1) * 39 + g);
    if (xcd != 0 && g >= 39) return;         // 56 idle blocks (balance 313 = 40 + 7*39)
    const int n0 = tile * 32;
    const int d = lane;

    // ---- stage x slice ----
    {
        int idx = tid;
        int t = idx >> 5, node = idx & 31;
        int n = n0 + node;
        xs[node * 12 + t] = (n < N_) ? x[(b * T_ + t) * N_ + n] : 0.f;
        idx = tid + 256;
        if (idx < 384) {
            t = idx >> 5; node = idx & 31; n = n0 + node;
            xs[node * 12 + t] = (n < N_) ? x[(b * T_ + t) * N_ + n] : 0.f;
        }
    }

    // ---- fused gather: 4 threads per (node,set), 12 channels for this b ----
    {
        float4* P4 = (float4*)&s_out[0][0];             // 256 threads x 3 float4 = 12 KB
        const int p = tid >> 2;                          // 0..63
        const int s = tid & 3;
        const int node = p & 31;
        const int set = p >> 5;                          // 0:A 1:C
        const int n = n0 + node;
        float4 a0 = {0,0,0,0}, a1 = {0,0,0,0}, a2 = {0,0,0,0};
        if (n < N_) {
            const int* sl = (set ? slotC : slotA) + n * CAP_;
            int dgRaw = (set ? curC : curA)[n];
            int dg = dgRaw < CAP_ ? dgRaw : CAP_;
            for (int j = s; j < dg; j += 4) {
                const float4* src = xt4 + (size_t)sl[j] * NQ_ + b * 3;
                float4 v0 = src[0], v1 = src[1], v2 = src[2];
                a0.x += v0.x; a0.y += v0.y; a0.z += v0.z; a0.w += v0.w;
                a1.x += v1.x; a1.y += v1.y; a1.z += v1.z; a1.w += v1.w;
                a2.x += v2.x; a2.y += v2.y; a2.z += v2.z; a2.w += v2.w;
            }
        }
        P4[tid * 3 + 0] = a0;
        P4[tid * 3 + 1] = a1;
        P4[tid * 3 + 2] = a2;
    }
    __syncthreads();
    {
        const float4* P4 = (const float4*)&s_out[0][0];
        if (tid < 192) {
            int p2 = tid / 3, q = tid - p2 * 3;          // pair, quad
            int node = p2 & 31, set = p2 >> 5;
            int n = n0 + node;
            float4 s0 = P4[(p2 * 4 + 0) * 3 + q];
            float4 s1 = P4[(p2 * 4 + 1) * 3 + q];
            float4 s2 = P4[(p2 * 4 + 2) * 3 + q];
            float4 s3 = P4[(p2 * 4 + 3) * 3 + q];
            float4 sum;
            sum.x = (s0.x + s1.x) + (s2.x + s3.x);
            sum.y = (s0.y + s1.y) + (s2.y + s3.y);
            sum.z = (s0.z + s1.z) + (s2.z + s3.z);
            sum.w = (s0.w + s1.w) + (s2.w + s3.w);
            int dgRaw = (n < N_) ? (set ? curC : curA)[n] : 0;
            float inv = 1.f / (float)(dgRaw > 0 ? dgRaw : 1);
            sum.x *= inv; sum.y *= inv; sum.z *= inv; sum.w *= inv;
            ((float4*)(set ? cs_ : as_))[node * 3 + q] = sum;
        } else {
            int i = tid - 192;                           // 0..63: 32 A-flags then 32 C-flags
            int node = i & 31, set = i >> 5;
            int n = n0 + node;
            float f = (n < N_ && (set ? curC : curA)[n] > 0) ? 1.f : 0.f;
            if (set) indC[node] = f; else indA[node] = f;
        }
    }

    // ---- per-lane composite weights ----
    float w[72];
    {
        const float4* wv = (const float4*)(par + d * 72);
#pragma unroll
        for (int k = 0; k < 18; ++k) ((float4*)w)[k] = wv[k];
    }
    const float ch0 = par[P_TAIL + 0 * 64 + d], ch1 = par[P_TAIL + 1 * 64 + d];
    const float cl0 = par[P_TAIL + 2 * 64 + d], cl1 = par[P_TAIL + 3 * 64 + d];
    const float cl2 = par[P_TAIL + 4 * 64 + d];
    const float ghn = g_hn[d], bhn = b_hn[d];
    const float gln = g_ln[d], bln = b_ln[d];
    const float ggn = g_gn[d], bgn = b_gn[d];
    const float bgd = bg[d];
    // softmax over 2 logits == sigmoid of the logit difference: fold Wa/ba to diff form
    const float wd0 = Wa[d * 2 + 0] - Wa[d * 2 + 1];
    const float wd1 = Wa[(64 + d) * 2 + 0] - Wa[(64 + d) * 2 + 1];
    const float bad = ba[0] - ba[1];

    __syncthreads();   // as_/cs_/ind ready; partial buffer dead -> s_out reusable

#pragma unroll 2
    for (int i = 0; i < 8; ++i) {
        const int nl = wave * 8 + i;
        float u[12], ua[12], uc[12];
#pragma unroll
        for (int k = 0; k < 3; ++k) {
            ((float4*)u)[k]  = ((const float4*)(xs  + nl * 12))[k];
            ((float4*)ua)[k] = ((const float4*)(as_ + nl * 12))[k];
            ((float4*)uc)[k] = ((const float4*)(cs_ + nl * 12))[k];
        }
        const float indd = indA[nl], indc = indC[nl];

        float acc_h = ch0 + indd * ch1;
        float acc_l = cl0 + indd * cl1 + indc * cl2;
        float acc_r = bgd;
#pragma unroll
        for (int t = 0; t < 12; ++t) {
            acc_h += u[t] * w[t]      + ua[t] * w[12 + t];
            acc_l += u[t] * w[24 + t] + ua[t] * w[36 + t] + uc[t] * w[48 + t];
            acc_r += u[t] * w[60 + t];
        }

        float v0 = wave_sum(acc_h);
        float v1 = wave_sum(acc_h * acc_h);
        float v2 = wave_sum(acc_l);
        float v3 = wave_sum(acc_l * acc_l);
        float v4 = wave_sum(acc_r);
        float v5 = wave_sum(acc_r * acc_r);

        const float mh = v0 * (1.f / 64.f);
        const float varh = fmaxf(v1 * (1.f / 64.f) - mh * mh, 0.f);
        float hn = (acc_h - mh) * rsqrtf(varh + EPS_) * ghn + bhn;
        float high = hn >= 0.f ? hn : 0.1f * hn;

        const float ml = v2 * (1.f / 64.f);
        const float varl = fmaxf(v3 * (1.f / 64.f) - ml * ml, 0.f);
        float lnv = (acc_l - ml) * rsqrtf(varl + EPS_) * gln + bln;
        float low = 0.5f * lnv * (1.f + erff(lnv * 0.70710678118654752f));

        const float mr = v4 * (1.f / 64.f);
        const float varr = fmaxf(v5 * (1.f / 64.f) - mr * mr, 0.f);
        float rn = (acc_r - mr) * rsqrtf(varr + EPS_) * ggn + bgn;

        float S = wave_sum(high * wd0 + low * wd1);
        float a0 = 1.f / (1.f + expf(-(S + bad)));
        float fused = a0 * high + (1.f - a0) * low + 0.3f * high + 0.3f * low + 0.1f * rn;

        s_out[0][d * 33 + nl] = fused;
        s_out[1][d * 33 + nl] = high;
        s_out[2][d * 33 + nl] = low;
    }
    __syncthreads();

    const int off1 = B_ * 64 * N_;
    const int off2 = 2 * B_ * 64 * N_;
    for (int e2 = tid; e2 < 64 * 32; e2 += 256) {
        int r = e2 >> 5, nl = e2 & 31;
        int n = n0 + nl;
        if (n < N_) {
            float* o = out + (b * 64 + r) * N_ + n;
            o[0]    = s_out[0][r * 33 + nl];
            o[off1] = s_out[1][r * 33 + nl];
            o[off2] = s_out[2][r * 33 + nl];
        }
    }
}

extern "C" void kernel_launch(void* const* d_in, const int* in_sizes, int n_in,
                              void* d_out, int out_size, void* d_ws, size_t ws_size,
                              hipStream_t stream)
{
    const float* x   = (const float*)d_in[0];
    const int* ei    = (const int*)d_in[1];
    const int* cei   = (const int*)d_in[2];
    const float* W_ht = (const float*)d_in[3];
    const float* b_ht = (const float*)d_in[4];
    const float* W_lt = (const float*)d_in[5];
    const float* b_lt = (const float*)d_in[6];
    const float* Ws_h = (const float*)d_in[7];
    const float* Wn_h = (const float*)d_in[8];
    const float* b_h  = (const float*)d_in[9];
    const float* Ws_l = (const float*)d_in[10];
    const float* Wn_l = (const float*)d_in[11];
    const float* Wc_l = (const float*)d_in[12];
    const float* b_l  = (const float*)d_in[13];
    const float* Whr  = (const float*)d_in[14];
    const float* bhr  = (const float*)d_in[15];
    const float* Wlr  = (const float*)d_in[16];
    const float* blr  = (const float*)d_in[17];
    const float* g_hn = (const float*)d_in[18];
    const float* b_hn = (const float*)d_in[19];
    const float* g_ln = (const float*)d_in[20];
    const float* b_ln = (const float*)d_in[21];
    const float* Wa   = (const float*)d_in[22];
    const float* ba   = (const float*)d_in[23];
    const float* Wg   = (const float*)d_in[24];
    const float* bg   = (const float*)d_in[25];
    const float* g_gn = (const float*)d_in[26];
    const float* b_gn = (const float*)d_in[27];

    char* ws = (char*)d_ws;
    float* par   = (float*)(ws + O_PAR);
    int* curA    = (int*)(ws + O_CURA);
    int* curC    = (int*)(ws + O_CURC);
    int* slotA   = (int*)(ws + O_SLOTA);
    int* slotC   = (int*)(ws + O_SLOTC);
    float* xt    = (float*)(ws + O_XT);

    hipMemsetAsync(ws + O_CURA, 0, O_SLOTA - O_CURA, stream);

    k1_kernel<<<NT64 + 1 + (2 * E_ + 255) / 256, 256, 0, stream>>>(
        x, xt, ei, cei, curA, curC, slotA, slotC,
        W_ht, b_ht, W_lt, b_lt, Ws_h, Wn_h, b_h,
        Ws_l, Wn_l, Wc_l, b_l, Whr, bhr, Wlr, blr, Wg, par);

    // 8 XCD x 40 tile-groups x 8 b = 2560 blocks (56 idle for 313-tile balance)
    main_kernel<<<8 * 40 * 8, 256, 0, stream>>>(
        x, par, (const float4*)xt, curA, curC, slotA, slotC,
        g_hn, b_hn, g_ln, b_ln, Wa, ba, bg, g_gn, b_gn, (float*)d_out);
}

// Round 4
// 208.511 us; speedup vs baseline: 3.9508x; 1.0401x over previous
//
#include <hip/hip_runtime.h>

#define B_ 8
#define T_ 12
#define N_ 10000
#define E_ 160000
#define NQ_ 24           // B_*T_/4 quads per node in xt
#define EPS_ 1e-5f
#define CAP_ 64          // neighbor bucket capacity (deg ~ Binom(160k,1e-4), max ~40)
#define NC32 313         // ceil(N_/32)
#define NT64 157         // ceil(N_/64) transpose tiles

// workspace byte offsets (16B-aligned)
#define O_PAR     0
#define O_CURA    24576
#define O_CURC    65536
#define O_SLOTA   106496
#define O_SLOTC   2666496
#define O_XT      5226496
// end ~9.07 MB

// par layout: [d][72] composite weights (a*12+t, a = ah,bh,al,bl,cl,ag), then 5x64 bias tails
#define P_TAIL 4608

// ---------------- DPP wave-64 sum (VALU pipe) ----------------
template<int CTRL>
__device__ __forceinline__ float dpp_add(float v) {
    int s = __builtin_amdgcn_update_dpp(0, __float_as_int(v), CTRL, 0xF, 0xF, true);
    return v + __int_as_float(s);
}
__device__ __forceinline__ float wave_sum(float v) {
    v = dpp_add<0x111>(v);   // row_shr:1
    v = dpp_add<0x112>(v);   // row_shr:2
    v = dpp_add<0x114>(v);   // row_shr:4
    v = dpp_add<0x118>(v);   // row_shr:8
    v = dpp_add<0x142>(v);   // row_bcast15
    v = dpp_add<0x143>(v);   // row_bcast31 -> lane63 = total
    return __int_as_float(__builtin_amdgcn_readlane(__float_as_int(v), 63));
}

// prep main task: one (t,d) pair -> 6 composite weight entries of par
__device__ __forceinline__ void prep_task(int task,
    const float* W_ht, const float* W_lt,
    const float* Ws_h, const float* Wn_h,
    const float* Ws_l, const float* Wn_l, const float* Wc_l,
    const float* Whr, const float* Wlr,
    const float* Wg, float* par)
{
    int t = task >> 6, d = task & 63;
    float ah = 0.f, bh = 0.f, al = 0.f, bl = 0.f, cl = 0.f;
    for (int k = 0; k < 64; ++k) {
        float msh = Ws_h[k * 64 + d] + 0.2f * Whr[k * 64 + d];
        float msl = Ws_l[k * 64 + d] + 0.2f * Wlr[k * 64 + d];
        float wht = W_ht[t * 64 + k];
        float wlt = W_lt[t * 64 + k];
        ah += wht * msh;
        bh += wht * Wn_h[k * 64 + d];
        al += wlt * msl;
        bl += wlt * Wn_l[k * 64 + d];
        cl += wlt * Wc_l[k * 64 + d];
    }
    par[d * 72 + 0 * 12 + t] = ah;
    par[d * 72 + 1 * 12 + t] = bh;
    par[d * 72 + 2 * 12 + t] = al;
    par[d * 72 + 3 * 12 + t] = bl;
    par[d * 72 + 4 * 12 + t] = cl;
    par[d * 72 + 5 * 12 + t] = 2.f * Wg[t * 64 + d];
}

// prep tail: bias composites (one d per thread)
__device__ __forceinline__ void prep_tail(int d,
    const float* b_ht, const float* b_lt,
    const float* Ws_h, const float* Wn_h, const float* b_h,
    const float* Ws_l, const float* Wn_l, const float* Wc_l, const float* b_l,
    const float* Whr, const float* bhr, const float* Wlr, const float* blr,
    float* par)
{
    float ch0 = b_h[d] + 0.2f * bhr[d];
    float ch1 = 0.f;
    float cl0 = b_l[d] + 0.2f * blr[d];
    float cl1 = 0.f, cl2 = 0.f;
    for (int k = 0; k < 64; ++k) {
        float bht = b_ht[k];
        float blt = b_lt[k];
        float msh = Ws_h[k * 64 + d] + 0.2f * Whr[k * 64 + d];
        float msl = Ws_l[k * 64 + d] + 0.2f * Wlr[k * 64 + d];
        ch0 += bht * msh;
        ch1 += bht * Wn_h[k * 64 + d];
        cl0 += blt * msl;
        cl1 += blt * Wn_l[k * 64 + d];
        cl2 += blt * Wc_l[k * 64 + d];
    }
    par[P_TAIL + 0 * 64 + d] = ch0;
    par[P_TAIL + 1 * 64 + d] = ch1;
    par[P_TAIL + 2 * 64 + d] = cl0;
    par[P_TAIL + 3 * 64 + d] = cl1;
    par[P_TAIL + 4 * 64 + d] = cl2;
}

// ---------------- k1: LDS-tiled transpose + prep (4 blocks) + bucket fill ----------------
// blocks [0,157): transpose; [157,160): prep main tasks (1 task/thread, was 3 on ONE block);
// block 160: prep bias tail; blocks [161, 161+1250): edge bucket fill
__global__ __launch_bounds__(256) void k1_kernel(
    const float* __restrict__ x, float* __restrict__ xt,
    const int* __restrict__ ei, const int* __restrict__ cei,
    int* __restrict__ curA, int* __restrict__ curC,
    int* __restrict__ slotA, int* __restrict__ slotC,
    const float* W_ht, const float* b_ht, const float* W_lt, const float* b_lt,
    const float* Ws_h, const float* Wn_h, const float* b_h,
    const float* Ws_l, const float* Wn_l, const float* Wc_l, const float* b_l,
    const float* Whr, const float* bhr, const float* Wlr, const float* blr,
    const float* Wg, float* par)
{
    __shared__ float tld[64 * 98];
    const int tid = threadIdx.x;
    const int blk = blockIdx.x;

    if (blk < NT64) {
        const int n0 = blk * 64;
        const int j = tid & 63;
        const int r0 = tid >> 6;
        const bool ok = (n0 + j) < N_;
#pragma unroll
        for (int rr = 0; rr < 24; ++rr) {
            int r = rr * 4 + r0;
            tld[j * 98 + r] = ok ? x[r * N_ + n0 + j] : 0.f;
        }
        __syncthreads();
        float4* xt4 = (float4*)xt;
#pragma unroll
        for (int it = 0; it < 6; ++it) {
            int idx = it * 256 + tid;
            int jj = idx / 24, q = idx - jj * 24;
            if (n0 + jj < N_) {
                float4 v;
                v.x = tld[jj * 98 + 4 * q + 0];
                v.y = tld[jj * 98 + 4 * q + 1];
                v.z = tld[jj * 98 + 4 * q + 2];
                v.w = tld[jj * 98 + 4 * q + 3];
                xt4[(size_t)(n0 + jj) * NQ_ + q] = v;
            }
        }
        return;
    }
    if (blk < NT64 + 3) {
        int task = (blk - NT64) * 256 + tid;   // 0..767
        prep_task(task, W_ht, W_lt, Ws_h, Wn_h, Ws_l, Wn_l, Wc_l, Whr, Wlr, Wg, par);
        return;
    }
    if (blk == NT64 + 3) {
        if (tid < 64)
            prep_tail(tid, b_ht, b_lt, Ws_h, Wn_h, b_h, Ws_l, Wn_l, Wc_l, b_l,
                      Whr, bhr, Wlr, blr, par);
        return;
    }
    int i = (blk - NT64 - 4) * 256 + tid;   // 0 .. 320000
    if (i < E_) {
        int dd = ei[E_ + i];
        int p = atomicAdd(&curA[dd], 1);
        if (p < CAP_) slotA[dd * CAP_ + p] = ei[i];
    } else if (i < 2 * E_) {
        int e = i - E_;
        int dd = cei[E_ + e];
        int p = atomicAdd(&curC[dd], 1);
        if (p < CAP_) slotC[dd * CAP_ + p] = cei[e];
    }
}

// ---------------- main: fused gather + per-row compute (32-node tiles) ----------------
// Block mapping b = blockIdx&7: under round-robin dispatch XCD == b, so each XCD reads
// only the b-slice of xt rows (measured best: FETCH 21.4 MB vs 30.1 MB for tile-co-location).
__global__ __launch_bounds__(256, 4) void main_kernel(
    const float* __restrict__ x, const float* __restrict__ par,
    const float4* __restrict__ xt4,
    const int* __restrict__ curA, const int* __restrict__ curC,
    const int* __restrict__ slotA, const int* __restrict__ slotC,
    const float* __restrict__ g_hn, const float* __restrict__ b_hn,
    const float* __restrict__ g_ln, const float* __restrict__ b_ln,
    const float* __restrict__ Wa, const float* __restrict__ ba,
    const float* __restrict__ bg, const float* __restrict__ g_gn,
    const float* __restrict__ b_gn,
    float* __restrict__ out)
{
    __shared__ __align__(16) float s_out[3][64 * 33];   // outputs; [0..12KB) aliased as gather partials
    __shared__ __align__(16) float xs[32 * 12];
    __shared__ __align__(16) float as_[32 * 12];
    __shared__ __align__(16) float cs_[32 * 12];
    __shared__ float indA[32];
    __shared__ float indC[32];

    const int tid = threadIdx.x;
    const int lane = tid & 63;
    const int wave = tid >> 6;
    const int b = blockIdx.x & 7;          // XCD-aligned under round-robin dispatch
    const int n0 = (blockIdx.x >> 3) * 32;
    const int d = lane;

    // ---- stage x slice ----
    {
        int idx = tid;
        int t = idx >> 5, node = idx & 31;
        int n = n0 + node;
        xs[node * 12 + t] = (n < N_) ? x[(b * T_ + t) * N_ + n] : 0.f;
        idx = tid + 256;
        if (idx < 384) {
            t = idx >> 5; node = idx & 31; n = n0 + node;
            xs[node * 12 + t] = (n < N_) ? x[(b * T_ + t) * N_ + n] : 0.f;
        }
    }

    // ---- fused gather: 4 threads per (node,set), 12 channels for this b ----
    {
        float4* P4 = (float4*)&s_out[0][0];             // 256 threads x 3 float4 = 12 KB
        const int p = tid >> 2;                          // 0..63
        const int s = tid & 3;
        const int node = p & 31;
        const int set = p >> 5;                          // 0:A 1:C
        const int n = n0 + node;
        float4 a0 = {0,0,0,0}, a1 = {0,0,0,0}, a2 = {0,0,0,0};
        if (n < N_) {
            const int* sl = (set ? slotC : slotA) + n * CAP_;
            int dgRaw = (set ? curC : curA)[n];
            int dg = dgRaw < CAP_ ? dgRaw : CAP_;
            for (int j = s; j < dg; j += 4) {
                const float4* src = xt4 + (size_t)sl[j] * NQ_ + b * 3;
                float4 v0 = src[0], v1 = src[1], v2 = src[2];
                a0.x += v0.x; a0.y += v0.y; a0.z += v0.z; a0.w += v0.w;
                a1.x += v1.x; a1.y += v1.y; a1.z += v1.z; a1.w += v1.w;
                a2.x += v2.x; a2.y += v2.y; a2.z += v2.z; a2.w += v2.w;
            }
        }
        P4[tid * 3 + 0] = a0;
        P4[tid * 3 + 1] = a1;
        P4[tid * 3 + 2] = a2;
    }
    __syncthreads();
    {
        const float4* P4 = (const float4*)&s_out[0][0];
        if (tid < 192) {
            int p2 = tid / 3, q = tid - p2 * 3;          // pair, quad
            int node = p2 & 31, set = p2 >> 5;
            int n = n0 + node;
            float4 s0 = P4[(p2 * 4 + 0) * 3 + q];
            float4 s1 = P4[(p2 * 4 + 1) * 3 + q];
            float4 s2 = P4[(p2 * 4 + 2) * 3 + q];
            float4 s3 = P4[(p2 * 4 + 3) * 3 + q];
            float4 sum;
            sum.x = (s0.x + s1.x) + (s2.x + s3.x);
            sum.y = (s0.y + s1.y) + (s2.y + s3.y);
            sum.z = (s0.z + s1.z) + (s2.z + s3.z);
            sum.w = (s0.w + s1.w) + (s2.w + s3.w);
            int dgRaw = (n < N_) ? (set ? curC : curA)[n] : 0;
            float inv = 1.f / (float)(dgRaw > 0 ? dgRaw : 1);
            sum.x *= inv; sum.y *= inv; sum.z *= inv; sum.w *= inv;
            ((float4*)(set ? cs_ : as_))[node * 3 + q] = sum;
        } else {
            int i = tid - 192;                           // 0..63: 32 A-flags then 32 C-flags
            int node = i & 31, set = i >> 5;
            int n = n0 + node;
            float f = (n < N_ && (set ? curC : curA)[n] > 0) ? 1.f : 0.f;
            if (set) indC[node] = f; else indA[node] = f;
        }
    }

    // ---- per-lane composite weights ----
    float w[72];
    {
        const float4* wv = (const float4*)(par + d * 72);
#pragma unroll
        for (int k = 0; k < 18; ++k) ((float4*)w)[k] = wv[k];
    }
    const float ch0 = par[P_TAIL + 0 * 64 + d], ch1 = par[P_TAIL + 1 * 64 + d];
    const float cl0 = par[P_TAIL + 2 * 64 + d], cl1 = par[P_TAIL + 3 * 64 + d];
    const float cl2 = par[P_TAIL + 4 * 64 + d];
    const float ghn = g_hn[d], bhn = b_hn[d];
    const float gln = g_ln[d], bln = b_ln[d];
    const float ggn = g_gn[d], bgn = b_gn[d];
    const float bgd = bg[d];
    // softmax over 2 logits == sigmoid of the logit difference: fold Wa/ba to diff form
    const float wd0 = Wa[d * 2 + 0] - Wa[d * 2 + 1];
    const float wd1 = Wa[(64 + d) * 2 + 0] - Wa[(64 + d) * 2 + 1];
    const float bad = ba[0] - ba[1];

    __syncthreads();   // as_/cs_/ind ready; partial buffer dead -> s_out reusable

#pragma unroll 2
    for (int i = 0; i < 8; ++i) {
        const int nl = wave * 8 + i;
        float u[12], ua[12], uc[12];
#pragma unroll
        for (int k = 0; k < 3; ++k) {
            ((float4*)u)[k]  = ((const float4*)(xs  + nl * 12))[k];
            ((float4*)ua)[k] = ((const float4*)(as_ + nl * 12))[k];
            ((float4*)uc)[k] = ((const float4*)(cs_ + nl * 12))[k];
        }
        const float indd = indA[nl], indc = indC[nl];

        float acc_h = ch0 + indd * ch1;
        float acc_l = cl0 + indd * cl1 + indc * cl2;
        float acc_r = bgd;
#pragma unroll
        for (int t = 0; t < 12; ++t) {
            acc_h += u[t] * w[t]      + ua[t] * w[12 + t];
            acc_l += u[t] * w[24 + t] + ua[t] * w[36 + t] + uc[t] * w[48 + t];
            acc_r += u[t] * w[60 + t];
        }

        float v0 = wave_sum(acc_h);
        float v1 = wave_sum(acc_h * acc_h);
        float v2 = wave_sum(acc_l);
        float v3 = wave_sum(acc_l * acc_l);
        float v4 = wave_sum(acc_r);
        float v5 = wave_sum(acc_r * acc_r);

        const float mh = v0 * (1.f / 64.f);
        const float varh = fmaxf(v1 * (1.f / 64.f) - mh * mh, 0.f);
        float hn = (acc_h - mh) * rsqrtf(varh + EPS_) * ghn + bhn;
        float high = hn >= 0.f ? hn : 0.1f * hn;

        const float ml = v2 * (1.f / 64.f);
        const float varl = fmaxf(v3 * (1.f / 64.f) - ml * ml, 0.f);
        float lnv = (acc_l - ml) * rsqrtf(varl + EPS_) * gln + bln;
        float low = 0.5f * lnv * (1.f + erff(lnv * 0.70710678118654752f));

        const float mr = v4 * (1.f / 64.f);
        const float varr = fmaxf(v5 * (1.f / 64.f) - mr * mr, 0.f);
        float rn = (acc_r - mr) * rsqrtf(varr + EPS_) * ggn + bgn;

        float S = wave_sum(high * wd0 + low * wd1);
        float a0 = 1.f / (1.f + expf(-(S + bad)));
        float fused = a0 * high + (1.f - a0) * low + 0.3f * high + 0.3f * low + 0.1f * rn;

        s_out[0][d * 33 + nl] = fused;
        s_out[1][d * 33 + nl] = high;
        s_out[2][d * 33 + nl] = low;
    }
    __syncthreads();

    const int off1 = B_ * 64 * N_;
    const int off2 = 2 * B_ * 64 * N_;
    for (int e2 = tid; e2 < 64 * 32; e2 += 256) {
        int r = e2 >> 5, nl = e2 & 31;
        int n = n0 + nl;
        if (n < N_) {
            float* o = out + (b * 64 + r) * N_ + n;
            o[0]    = s_out[0][r * 33 + nl];
            o[off1] = s_out[1][r * 33 + nl];
            o[off2] = s_out[2][r * 33 + nl];
        }
    }
}

extern "C" void kernel_launch(void* const* d_in, const int* in_sizes, int n_in,
                              void* d_out, int out_size, void* d_ws, size_t ws_size,
                              hipStream_t stream)
{
    const float* x   = (const float*)d_in[0];
    const int* ei    = (const int*)d_in[1];
    const int* cei   = (const int*)d_in[2];
    const float* W_ht = (const float*)d_in[3];
    const float* b_ht = (const float*)d_in[4];
    const float* W_lt = (const float*)d_in[5];
    const float* b_lt = (const float*)d_in[6];
    const float* Ws_h = (const float*)d_in[7];
    const float* Wn_h = (const float*)d_in[8];
    const float* b_h  = (const float*)d_in[9];
    const float* Ws_l = (const float*)d_in[10];
    const float* Wn_l = (const float*)d_in[11];
    const float* Wc_l = (const float*)d_in[12];
    const float* b_l  = (const float*)d_in[13];
    const float* Whr  = (const float*)d_in[14];
    const float* bhr  = (const float*)d_in[15];
    const float* Wlr  = (const float*)d_in[16];
    const float* blr  = (const float*)d_in[17];
    const float* g_hn = (const float*)d_in[18];
    const float* b_hn = (const float*)d_in[19];
    const float* g_ln = (const float*)d_in[20];
    const float* b_ln = (const float*)d_in[21];
    const float* Wa   = (const float*)d_in[22];
    const float* ba   = (const float*)d_in[23];
    const float* Wg   = (const float*)d_in[24];
    const float* bg   = (const float*)d_in[25];
    const float* g_gn = (const float*)d_in[26];
    const float* b_gn = (const float*)d_in[27];

    char* ws = (char*)d_ws;
    float* par   = (float*)(ws + O_PAR);
    int* curA    = (int*)(ws + O_CURA);
    int* curC    = (int*)(ws + O_CURC);
    int* slotA   = (int*)(ws + O_SLOTA);
    int* slotC   = (int*)(ws + O_SLOTC);
    float* xt    = (float*)(ws + O_XT);

    hipMemsetAsync(ws + O_CURA, 0, O_SLOTA - O_CURA, stream);

    k1_kernel<<<NT64 + 4 + (2 * E_ + 255) / 256, 256, 0, stream>>>(
        x, xt, ei, cei, curA, curC, slotA, slotC,
        W_ht, b_ht, W_lt, b_lt, Ws_h, Wn_h, b_h,
        Ws_l, Wn_l, Wc_l, b_l, Whr, bhr, Wlr, blr, Wg, par);

    main_kernel<<<NC32 * 8, 256, 0, stream>>>(
        x, par, (const float4*)xt, curA, curC, slotA, slotC,
        g_hn, b_hn, g_ln, b_ln, Wa, ba, bg, g_gn, b_gn, (float*)d_out);
}

// Round 5
// 204.748 us; speedup vs baseline: 4.0234x; 1.0184x over previous
//
#include <hip/hip_runtime.h>

#define B_ 8
#define T_ 12
#define N_ 10000
#define E_ 160000
#define NQ_ 24           // B_*T_/4 quads per node in xt
#define EPS_ 1e-5f
#define CAP_ 64          // neighbor bucket capacity (deg ~ Binom(160k,1e-4), max ~40)
#define NC32 313         // ceil(N_/32)
#define NT64 157         // ceil(N_/64) transpose tiles

// workspace byte offsets (16B-aligned)
#define O_PAR     0
#define O_CURA    24576
#define O_CURC    65536
#define O_SLOTA   106496
#define O_SLOTC   2666496
#define O_XT      5226496
// end ~9.07 MB

// par layout: [d][72] composite weights (a*12+t, a = ah,bh,al,bl,cl,ag), then 5x64 bias tails
#define P_TAIL 4608

// ---------------- DPP wave-64 sum (VALU pipe) ----------------
template<int CTRL>
__device__ __forceinline__ float dpp_add(float v) {
    int s = __builtin_amdgcn_update_dpp(0, __float_as_int(v), CTRL, 0xF, 0xF, true);
    return v + __int_as_float(s);
}
__device__ __forceinline__ float wave_sum(float v) {
    v = dpp_add<0x111>(v);   // row_shr:1
    v = dpp_add<0x112>(v);   // row_shr:2
    v = dpp_add<0x114>(v);   // row_shr:4
    v = dpp_add<0x118>(v);   // row_shr:8
    v = dpp_add<0x142>(v);   // row_bcast15
    v = dpp_add<0x143>(v);   // row_bcast31 -> lane63 = total
    return __int_as_float(__builtin_amdgcn_readlane(__float_as_int(v), 63));
}

// prep main task: one (t,d) pair -> 6 composite weight entries of par
__device__ __forceinline__ void prep_task(int task,
    const float* W_ht, const float* W_lt,
    const float* Ws_h, const float* Wn_h,
    const float* Ws_l, const float* Wn_l, const float* Wc_l,
    const float* Whr, const float* Wlr,
    const float* Wg, float* par)
{
    int t = task >> 6, d = task & 63;
    float ah = 0.f, bh = 0.f, al = 0.f, bl = 0.f, cl = 0.f;
    for (int k = 0; k < 64; ++k) {
        float msh = Ws_h[k * 64 + d] + 0.2f * Whr[k * 64 + d];
        float msl = Ws_l[k * 64 + d] + 0.2f * Wlr[k * 64 + d];
        float wht = W_ht[t * 64 + k];
        float wlt = W_lt[t * 64 + k];
        ah += wht * msh;
        bh += wht * Wn_h[k * 64 + d];
        al += wlt * msl;
        bl += wlt * Wn_l[k * 64 + d];
        cl += wlt * Wc_l[k * 64 + d];
    }
    par[d * 72 + 0 * 12 + t] = ah;
    par[d * 72 + 1 * 12 + t] = bh;
    par[d * 72 + 2 * 12 + t] = al;
    par[d * 72 + 3 * 12 + t] = bl;
    par[d * 72 + 4 * 12 + t] = cl;
    par[d * 72 + 5 * 12 + t] = 2.f * Wg[t * 64 + d];
}

// prep tail: bias composites (one d per thread)
__device__ __forceinline__ void prep_tail(int d,
    const float* b_ht, const float* b_lt,
    const float* Ws_h, const float* Wn_h, const float* b_h,
    const float* Ws_l, const float* Wn_l, const float* Wc_l, const float* b_l,
    const float* Whr, const float* bhr, const float* Wlr, const float* blr,
    float* par)
{
    float ch0 = b_h[d] + 0.2f * bhr[d];
    float ch1 = 0.f;
    float cl0 = b_l[d] + 0.2f * blr[d];
    float cl1 = 0.f, cl2 = 0.f;
    for (int k = 0; k < 64; ++k) {
        float bht = b_ht[k];
        float blt = b_lt[k];
        float msh = Ws_h[k * 64 + d] + 0.2f * Whr[k * 64 + d];
        float msl = Ws_l[k * 64 + d] + 0.2f * Wlr[k * 64 + d];
        ch0 += bht * msh;
        ch1 += bht * Wn_h[k * 64 + d];
        cl0 += blt * msl;
        cl1 += blt * Wn_l[k * 64 + d];
        cl2 += blt * Wc_l[k * 64 + d];
    }
    par[P_TAIL + 0 * 64 + d] = ch0;
    par[P_TAIL + 1 * 64 + d] = ch1;
    par[P_TAIL + 2 * 64 + d] = cl0;
    par[P_TAIL + 3 * 64 + d] = cl1;
    par[P_TAIL + 4 * 64 + d] = cl2;
}

// ---------------- k1: LDS-tiled transpose + prep (4 blocks) + bucket fill ----------------
// blocks [0,157): transpose; [157,160): prep main tasks; block 160: prep bias tail;
// blocks [161, 161+313): edge bucket fill, 4 edges/thread via int4 loads
__global__ __launch_bounds__(256) void k1_kernel(
    const float* __restrict__ x, float* __restrict__ xt,
    const int* __restrict__ ei, const int* __restrict__ cei,
    int* __restrict__ curA, int* __restrict__ curC,
    int* __restrict__ slotA, int* __restrict__ slotC,
    const float* W_ht, const float* b_ht, const float* W_lt, const float* b_lt,
    const float* Ws_h, const float* Wn_h, const float* b_h,
    const float* Ws_l, const float* Wn_l, const float* Wc_l, const float* b_l,
    const float* Whr, const float* bhr, const float* Wlr, const float* blr,
    const float* Wg, float* par)
{
    __shared__ float tld[64 * 98];
    const int tid = threadIdx.x;
    const int blk = blockIdx.x;

    if (blk < NT64) {
        const int n0 = blk * 64;
        const int j = tid & 63;
        const int r0 = tid >> 6;
        const bool ok = (n0 + j) < N_;
#pragma unroll
        for (int rr = 0; rr < 24; ++rr) {
            int r = rr * 4 + r0;
            tld[j * 98 + r] = ok ? x[r * N_ + n0 + j] : 0.f;
        }
        __syncthreads();
        float4* xt4 = (float4*)xt;
#pragma unroll
        for (int it = 0; it < 6; ++it) {
            int idx = it * 256 + tid;
            int jj = idx / 24, q = idx - jj * 24;
            if (n0 + jj < N_) {
                float4 v;
                v.x = tld[jj * 98 + 4 * q + 0];
                v.y = tld[jj * 98 + 4 * q + 1];
                v.z = tld[jj * 98 + 4 * q + 2];
                v.w = tld[jj * 98 + 4 * q + 3];
                xt4[(size_t)(n0 + jj) * NQ_ + q] = v;
            }
        }
        return;
    }
    if (blk < NT64 + 3) {
        int task = (blk - NT64) * 256 + tid;   // 0..767
        prep_task(task, W_ht, W_lt, Ws_h, Wn_h, Ws_l, Wn_l, Wc_l, Whr, Wlr, Wg, par);
        return;
    }
    if (blk == NT64 + 3) {
        if (tid < 64)
            prep_tail(tid, b_ht, b_lt, Ws_h, Wn_h, b_h, Ws_l, Wn_l, Wc_l, b_l,
                      Whr, bhr, Wlr, blr, par);
        return;
    }
    // ---- edge fill: 4 edges/thread, E_/4 = 40000 quads per set ----
    int e4 = (blk - NT64 - 4) * 256 + tid;     // 0 .. 80000
    if (e4 < E_ / 4) {
        int4 s4 = *(const int4*)&ei[4 * e4];
        int4 d4 = *(const int4*)&ei[E_ + 4 * e4];
        int p0 = atomicAdd(&curA[d4.x], 1);
        int p1 = atomicAdd(&curA[d4.y], 1);
        int p2 = atomicAdd(&curA[d4.z], 1);
        int p3 = atomicAdd(&curA[d4.w], 1);
        if (p0 < CAP_) slotA[d4.x * CAP_ + p0] = s4.x;
        if (p1 < CAP_) slotA[d4.y * CAP_ + p1] = s4.y;
        if (p2 < CAP_) slotA[d4.z * CAP_ + p2] = s4.z;
        if (p3 < CAP_) slotA[d4.w * CAP_ + p3] = s4.w;
    } else if (e4 < 2 * (E_ / 4)) {
        int q = e4 - E_ / 4;
        int4 s4 = *(const int4*)&cei[4 * q];
        int4 d4 = *(const int4*)&cei[E_ + 4 * q];
        int p0 = atomicAdd(&curC[d4.x], 1);
        int p1 = atomicAdd(&curC[d4.y], 1);
        int p2 = atomicAdd(&curC[d4.z], 1);
        int p3 = atomicAdd(&curC[d4.w], 1);
        if (p0 < CAP_) slotC[d4.x * CAP_ + p0] = s4.x;
        if (p1 < CAP_) slotC[d4.y * CAP_ + p1] = s4.y;
        if (p2 < CAP_) slotC[d4.z * CAP_ + p2] = s4.z;
        if (p3 < CAP_) slotC[d4.w * CAP_ + p3] = s4.w;
    }
}

// ---------------- main: fused gather + per-row compute (32-node tiles) ----------------
// Block mapping b = blockIdx&7: under round-robin dispatch XCD == b, so each XCD reads
// only the b-slice of xt rows (measured best: FETCH 21.4 MB vs 30.1 MB for tile-co-location).
__global__ __launch_bounds__(256, 4) void main_kernel(
    const float* __restrict__ x, const float* __restrict__ par,
    const float4* __restrict__ xt4,
    const int* __restrict__ curA, const int* __restrict__ curC,
    const int* __restrict__ slotA, const int* __restrict__ slotC,
    const float* __restrict__ g_hn, const float* __restrict__ b_hn,
    const float* __restrict__ g_ln, const float* __restrict__ b_ln,
    const float* __restrict__ Wa, const float* __restrict__ ba,
    const float* __restrict__ bg, const float* __restrict__ g_gn,
    const float* __restrict__ b_gn,
    float* __restrict__ out)
{
    __shared__ __align__(16) float s_out[3][64 * 33];   // outputs; [0..12KB) aliased as gather partials
    __shared__ __align__(16) float xs[32 * 12];
    __shared__ __align__(16) float as_[32 * 12];
    __shared__ __align__(16) float cs_[32 * 12];
    __shared__ float indA[32];
    __shared__ float indC[32];

    const int tid = threadIdx.x;
    const int lane = tid & 63;
    const int wave = tid >> 6;
    const int b = blockIdx.x & 7;          // XCD-aligned under round-robin dispatch
    const int n0 = (blockIdx.x >> 3) * 32;
    const int d = lane;

    // ---- stage x slice ----
    {
        int idx = tid;
        int t = idx >> 5, node = idx & 31;
        int n = n0 + node;
        xs[node * 12 + t] = (n < N_) ? x[(b * T_ + t) * N_ + n] : 0.f;
        idx = tid + 256;
        if (idx < 384) {
            t = idx >> 5; node = idx & 31; n = n0 + node;
            xs[node * 12 + t] = (n < N_) ? x[(b * T_ + t) * N_ + n] : 0.f;
        }
    }

    // ---- fused gather: 4 threads per (node,set), 12 channels for this b ----
    // unrolled x2: 6 float4 loads in flight per iteration (latency hiding)
    {
        float4* P4 = (float4*)&s_out[0][0];             // 256 threads x 3 float4 = 12 KB
        const int p = tid >> 2;                          // 0..63
        const int s = tid & 3;
        const int node = p & 31;
        const int set = p >> 5;                          // 0:A 1:C
        const int n = n0 + node;
        float4 a0 = {0,0,0,0}, a1 = {0,0,0,0}, a2 = {0,0,0,0};
        if (n < N_) {
            const int* sl = (set ? slotC : slotA) + n * CAP_;
            int dgRaw = (set ? curC : curA)[n];
            int dg = dgRaw < CAP_ ? dgRaw : CAP_;
            int j = s;
            for (; j + 4 < dg; j += 8) {
                const float4* src0 = xt4 + (size_t)sl[j]     * NQ_ + b * 3;
                const float4* src1 = xt4 + (size_t)sl[j + 4] * NQ_ + b * 3;
                float4 v0 = src0[0], v1 = src0[1], v2 = src0[2];
                float4 v3 = src1[0], v4 = src1[1], v5 = src1[2];
                a0.x += v0.x + v3.x; a0.y += v0.y + v3.y; a0.z += v0.z + v3.z; a0.w += v0.w + v3.w;
                a1.x += v1.x + v4.x; a1.y += v1.y + v4.y; a1.z += v1.z + v4.z; a1.w += v1.w + v4.w;
                a2.x += v2.x + v5.x; a2.y += v2.y + v5.y; a2.z += v2.z + v5.z; a2.w += v2.w + v5.w;
            }
            if (j < dg) {
                const float4* src = xt4 + (size_t)sl[j] * NQ_ + b * 3;
                float4 v0 = src[0], v1 = src[1], v2 = src[2];
                a0.x += v0.x; a0.y += v0.y; a0.z += v0.z; a0.w += v0.w;
                a1.x += v1.x; a1.y += v1.y; a1.z += v1.z; a1.w += v1.w;
                a2.x += v2.x; a2.y += v2.y; a2.z += v2.z; a2.w += v2.w;
            }
        }
        P4[tid * 3 + 0] = a0;
        P4[tid * 3 + 1] = a1;
        P4[tid * 3 + 2] = a2;
    }
    __syncthreads();
    {
        const float4* P4 = (const float4*)&s_out[0][0];
        if (tid < 192) {
            int p2 = tid / 3, q = tid - p2 * 3;          // pair, quad
            int node = p2 & 31, set = p2 >> 5;
            int n = n0 + node;
            float4 s0 = P4[(p2 * 4 + 0) * 3 + q];
            float4 s1 = P4[(p2 * 4 + 1) * 3 + q];
            float4 s2 = P4[(p2 * 4 + 2) * 3 + q];
            float4 s3 = P4[(p2 * 4 + 3) * 3 + q];
            float4 sum;
            sum.x = (s0.x + s1.x) + (s2.x + s3.x);
            sum.y = (s0.y + s1.y) + (s2.y + s3.y);
            sum.z = (s0.z + s1.z) + (s2.z + s3.z);
            sum.w = (s0.w + s1.w) + (s2.w + s3.w);
            int dgRaw = (n < N_) ? (set ? curC : curA)[n] : 0;
            float inv = __builtin_amdgcn_rcpf((float)(dgRaw > 0 ? dgRaw : 1));
            sum.x *= inv; sum.y *= inv; sum.z *= inv; sum.w *= inv;
            ((float4*)(set ? cs_ : as_))[node * 3 + q] = sum;
        } else {
            int i = tid - 192;                           // 0..63: 32 A-flags then 32 C-flags
            int node = i & 31, set = i >> 5;
            int n = n0 + node;
            float f = (n < N_ && (set ? curC : curA)[n] > 0) ? 1.f : 0.f;
            if (set) indC[node] = f; else indA[node] = f;
        }
    }

    // ---- per-lane composite weights ----
    float w[72];
    {
        const float4* wv = (const float4*)(par + d * 72);
#pragma unroll
        for (int k = 0; k < 18; ++k) ((float4*)w)[k] = wv[k];
    }
    const float ch0 = par[P_TAIL + 0 * 64 + d], ch1 = par[P_TAIL + 1 * 64 + d];
    const float cl0 = par[P_TAIL + 2 * 64 + d], cl1 = par[P_TAIL + 3 * 64 + d];
    const float cl2 = par[P_TAIL + 4 * 64 + d];
    const float ghn = g_hn[d], bhn = b_hn[d];
    const float gln = g_ln[d], bln = b_ln[d];
    const float ggn = g_gn[d], bgn = b_gn[d];
    const float bgd = bg[d];
    // softmax over 2 logits == sigmoid of the logit difference: fold Wa/ba to diff form
    const float wd0 = Wa[d * 2 + 0] - Wa[d * 2 + 1];
    const float wd1 = Wa[(64 + d) * 2 + 0] - Wa[(64 + d) * 2 + 1];
    const float bad = ba[0] - ba[1];

    __syncthreads();   // as_/cs_/ind ready; partial buffer dead -> s_out reusable

#pragma unroll 2
    for (int i = 0; i < 8; ++i) {
        const int nl = wave * 8 + i;
        float u[12], ua[12], uc[12];
#pragma unroll
        for (int k = 0; k < 3; ++k) {
            ((float4*)u)[k]  = ((const float4*)(xs  + nl * 12))[k];
            ((float4*)ua)[k] = ((const float4*)(as_ + nl * 12))[k];
            ((float4*)uc)[k] = ((const float4*)(cs_ + nl * 12))[k];
        }
        const float indd = indA[nl], indc = indC[nl];

        float acc_h = ch0 + indd * ch1;
        float acc_l = cl0 + indd * cl1 + indc * cl2;
        float acc_r = bgd;
#pragma unroll
        for (int t = 0; t < 12; ++t) {
            acc_h += u[t] * w[t]      + ua[t] * w[12 + t];
            acc_l += u[t] * w[24 + t] + ua[t] * w[36 + t] + uc[t] * w[48 + t];
            acc_r += u[t] * w[60 + t];
        }

        float v0 = wave_sum(acc_h);
        float v1 = wave_sum(acc_h * acc_h);
        float v2 = wave_sum(acc_l);
        float v3 = wave_sum(acc_l * acc_l);
        float v4 = wave_sum(acc_r);
        float v5 = wave_sum(acc_r * acc_r);

        const float mh = v0 * (1.f / 64.f);
        const float varh = fmaxf(v1 * (1.f / 64.f) - mh * mh, 0.f);
        float hn = (acc_h - mh) * rsqrtf(varh + EPS_) * ghn + bhn;
        float high = hn >= 0.f ? hn : 0.1f * hn;

        const float ml = v2 * (1.f / 64.f);
        const float varl = fmaxf(v3 * (1.f / 64.f) - ml * ml, 0.f);
        float lnv = (acc_l - ml) * rsqrtf(varl + EPS_) * gln + bln;
        float low = 0.5f * lnv * (1.f + erff(lnv * 0.70710678118654752f));

        const float mr = v4 * (1.f / 64.f);
        const float varr = fmaxf(v5 * (1.f / 64.f) - mr * mr, 0.f);
        float rn = (acc_r - mr) * rsqrtf(varr + EPS_) * ggn + bgn;

        // stage high/low before the dependent logit reduction (stores overlap S-chain)
        s_out[1][d * 33 + nl] = high;
        s_out[2][d * 33 + nl] = low;

        float S = wave_sum(high * wd0 + low * wd1);
        float a0 = __builtin_amdgcn_rcpf(1.f + __expf(-(S + bad)));
        float fused = a0 * high + (1.f - a0) * low + 0.3f * high + 0.3f * low + 0.1f * rn;

        s_out[0][d * 33 + nl] = fused;
    }
    __syncthreads();

    const int off1 = B_ * 64 * N_;
    const int off2 = 2 * B_ * 64 * N_;
    for (int e2 = tid; e2 < 64 * 32; e2 += 256) {
        int r = e2 >> 5, nl = e2 & 31;
        int n = n0 + nl;
        if (n < N_) {
            float* o = out + (b * 64 + r) * N_ + n;
            o[0]    = s_out[0][r * 33 + nl];
            o[off1] = s_out[1][r * 33 + nl];
            o[off2] = s_out[2][r * 33 + nl];
        }
    }
}

extern "C" void kernel_launch(void* const* d_in, const int* in_sizes, int n_in,
                              void* d_out, int out_size, void* d_ws, size_t ws_size,
                              hipStream_t stream)
{
    const float* x   = (const float*)d_in[0];
    const int* ei    = (const int*)d_in[1];
    const int* cei   = (const int*)d_in[2];
    const float* W_ht = (const float*)d_in[3];
    const float* b_ht = (const float*)d_in[4];
    const float* W_lt = (const float*)d_in[5];
    const float* b_lt = (const float*)d_in[6];
    const float* Ws_h = (const float*)d_in[7];
    const float* Wn_h = (const float*)d_in[8];
    const float* b_h  = (const float*)d_in[9];
    const float* Ws_l = (const float*)d_in[10];
    const float* Wn_l = (const float*)d_in[11];
    const float* Wc_l = (const float*)d_in[12];
    const float* b_l  = (const float*)d_in[13];
    const float* Whr  = (const float*)d_in[14];
    const float* bhr  = (const float*)d_in[15];
    const float* Wlr  = (const float*)d_in[16];
    const float* blr  = (const float*)d_in[17];
    const float* g_hn = (const float*)d_in[18];
    const float* b_hn = (const float*)d_in[19];
    const float* g_ln = (const float*)d_in[20];
    const float* b_ln = (const float*)d_in[21];
    const float* Wa   = (const float*)d_in[22];
    const float* ba   = (const float*)d_in[23];
    const float* Wg   = (const float*)d_in[24];
    const float* bg   = (const float*)d_in[25];
    const float* g_gn = (const float*)d_in[26];
    const float* b_gn = (const float*)d_in[27];

    char* ws = (char*)d_ws;
    float* par   = (float*)(ws + O_PAR);
    int* curA    = (int*)(ws + O_CURA);
    int* curC    = (int*)(ws + O_CURC);
    int* slotA   = (int*)(ws + O_SLOTA);
    int* slotC   = (int*)(ws + O_SLOTC);
    float* xt    = (float*)(ws + O_XT);

    hipMemsetAsync(ws + O_CURA, 0, O_SLOTA - O_CURA, stream);

    // 157 transpose + 4 prep + 313 edge-fill (4 edges/thread) = 474 blocks
    k1_kernel<<<NT64 + 4 + 313, 256, 0, stream>>>(
        x, xt, ei, cei, curA, curC, slotA, slotC,
        W_ht, b_ht, W_lt, b_lt, Ws_h, Wn_h, b_h,
        Ws_l, Wn_l, Wc_l, b_l, Whr, bhr, Wlr, blr, Wg, par);

    main_kernel<<<NC32 * 8, 256, 0, stream>>>(
        x, par, (const float4*)xt, curA, curC, slotA, slotC,
        g_hn, b_hn, g_ln, b_ln, Wa, ba, bg, g_gn, b_gn, (float*)d_out);
}